// Round 4
// baseline (485.172 us; speedup 1.0000x reference)
//
#include <hip/hip_runtime.h>
#include <hip/hip_bf16.h>

#define BB 4
#define NN 2048
#define DD 1024
#define HH 16

using bf16 = __hip_bfloat16;
typedef __attribute__((ext_vector_type(8))) short bf16x8s;
typedef __attribute__((ext_vector_type(4))) float f32x4;

#define GLOAD_LDS16(gp, lp)                                                   \
  __builtin_amdgcn_global_load_lds(                                           \
      (const __attribute__((address_space(1))) void*)(gp),                    \
      (__attribute__((address_space(3))) void*)(lp), 16, 0, 0)

// ---------------- cast f32 -> bf16 (vectorized x4) ----------------
__global__ void cast_f32_bf16(const float* __restrict__ in, bf16* __restrict__ out, int n) {
  int i = (blockIdx.x * blockDim.x + threadIdx.x) * 4;
  if (i >= n) return;
  float4 v = *reinterpret_cast<const float4*>(in + i);
  ushort4 o;
  bf16 t0 = __float2bfloat16(v.x); o.x = *reinterpret_cast<unsigned short*>(&t0);
  bf16 t1 = __float2bfloat16(v.y); o.y = *reinterpret_cast<unsigned short*>(&t1);
  bf16 t2 = __float2bfloat16(v.z); o.z = *reinterpret_cast<unsigned short*>(&t2);
  bf16 t3 = __float2bfloat16(v.w); o.w = *reinterpret_cast<unsigned short*>(&t3);
  *reinterpret_cast<ushort4*>(out + i) = o;
}

// ---------------- mask prep: maskL = mask * log2(e)  (exp2-domain softmax) ----------------
__global__ void mask_prep(const float* __restrict__ in, float* __restrict__ out, int n) {
  int i = (blockIdx.x * blockDim.x + threadIdx.x) * 4;
  if (i >= n) return;
  float4 v = *reinterpret_cast<const float4*>(in + i);
  const float c = 1.4426950408889634f;
  v.x *= c; v.y *= c; v.z *= c; v.w *= c;
  *reinterpret_cast<float4*>(out + i) = v;
}

// ---------------- transpose + cast: in[R,C] f32 -> out[C,R] bf16 ----------------
__global__ void transpose_cast(const float* __restrict__ in, bf16* __restrict__ out, int R, int C) {
  __shared__ float t[32][33];
  int c0 = blockIdx.x * 32, r0 = blockIdx.y * 32;
  int tx = threadIdx.x, ty = threadIdx.y;  // block (32,8)
#pragma unroll
  for (int i = 0; i < 4; i++)
    t[ty + i * 8][tx] = in[(size_t)(r0 + ty + i * 8) * C + c0 + tx];
  __syncthreads();
#pragma unroll
  for (int i = 0; i < 4; i++)
    out[(size_t)(c0 + ty + i * 8) * R + r0 + tx] = __float2bfloat16(t[tx][ty + i * 8]);
}

// ---------------- bf16->bf16 transpose of V into per-head layout ----------------
// Vb [B*N][D] -> Vt [B*H][64][N]  (Vt[bh][d][n] = Vb[b*N+n][h*64+d])
__global__ void transpose_v(const bf16* __restrict__ Vb, bf16* __restrict__ Vt) {
  __shared__ short t[32][33];
  int bh = blockIdx.z; int b = bh >> 4, h = bh & 15;
  int n0 = blockIdx.x * 32, d0 = blockIdx.y * 32;
  int tx = threadIdx.x, ty = threadIdx.y;  // block (32,8)
#pragma unroll
  for (int i = 0; i < 4; i++)
    t[ty + i * 8][tx] = reinterpret_cast<const short*>(Vb)[
        (size_t)(b * NN + n0 + ty + i * 8) * DD + h * 64 + d0 + tx];
  __syncthreads();
#pragma unroll
  for (int i = 0; i < 4; i++)
    reinterpret_cast<short*>(Vt)[(size_t)(bh * 64 + d0 + ty + i * 8) * NN + n0 + tx] =
        t[tx][ty + i * 8];
}

// ---------------- bf16 MFMA GEMM: C[M,Nc] = scale*(A[M,K] * BT[Nc,K]^T + bias (+rowadd)) ----
// 128x128 tile, BK=64, 4 waves (2x2). global_load_lds width=16 into linear [128][64] LDS;
// XOR chunk-swizzle on global source + ds_read (rule #21).
template <int OUT_BF16, int HAS_ROWADD>
__global__ __launch_bounds__(256) void gemm_bt(
    const bf16* __restrict__ A, const bf16* __restrict__ BT, void* __restrict__ Cout,
    const float* __restrict__ bias, const float* __restrict__ rowadd,
    int M, int Nc, int K, float scale) {
  __shared__ short As[128 * 64];
  __shared__ short Bs[128 * 64];
  const int tid = threadIdx.x;
  const int l = tid & 63, w = tid >> 6;
  const int wr = (w >> 1) * 64, wc = (w & 1) * 64;
  const int brow = blockIdx.y * 128, bcol = blockIdx.x * 128;
  const int lr = l & 15, lg = l >> 4;
  const int swz = lr & 7;
  f32x4 acc[4][4] = {};
  for (int k0 = 0; k0 < K; k0 += 64) {
#pragma unroll
    for (int i = 0; i < 4; i++) {
      int c = i * 256 + tid;          // chunk index 0..1023 (16B chunks)
      int row = c >> 3, gch = (c & 7) ^ (row & 7);
      short* lA = (short*)As + (size_t)(i * 256 + w * 64) * 8;  // wave-uniform dest
      GLOAD_LDS16(A + (size_t)(brow + row) * K + k0 + gch * 8, lA);
      short* lB = (short*)Bs + (size_t)(i * 256 + w * 64) * 8;
      GLOAD_LDS16(BT + (size_t)(bcol + row) * K + k0 + gch * 8, lB);
    }
    __syncthreads();
#pragma unroll
    for (int t = 0; t < 2; t++) {
      bf16x8s a[4], bfr[4];
#pragma unroll
      for (int m = 0; m < 4; m++)
        a[m] = *reinterpret_cast<const bf16x8s*>(
            &As[(wr + m * 16 + lr) * 64 + ((t * 4 + lg) ^ swz) * 8]);
#pragma unroll
      for (int n = 0; n < 4; n++)
        bfr[n] = *reinterpret_cast<const bf16x8s*>(
            &Bs[(wc + n * 16 + lr) * 64 + ((t * 4 + lg) ^ swz) * 8]);
#pragma unroll
      for (int m = 0; m < 4; m++)
#pragma unroll
        for (int n = 0; n < 4; n++)
          acc[m][n] = __builtin_amdgcn_mfma_f32_16x16x32_bf16(a[m], bfr[n], acc[m][n], 0, 0, 0);
    }
    __syncthreads();
  }
#pragma unroll
  for (int m = 0; m < 4; m++) {
#pragma unroll
    for (int n = 0; n < 4; n++) {
      int col = bcol + wc + n * 16 + lr;
      float bv = bias[col];
#pragma unroll
      for (int r = 0; r < 4; r++) {
        int row = brow + wr + m * 16 + (l >> 4) * 4 + r;
        float v = acc[m][n][r] + bv;
        if (HAS_ROWADD) v += rowadd[(size_t)(row & (NN - 1)) * Nc + col];
        v *= scale;
        if (OUT_BF16)
          reinterpret_cast<bf16*>(Cout)[(size_t)row * Nc + col] = __float2bfloat16(v);
        else
          reinterpret_cast<float*>(Cout)[(size_t)row * Nc + col] = v;
      }
    }
  }
}

// ---------------- flash attention, exp2-domain, defer-max, LDS mask tile ----------------
// grid (N/64, H, B), 256 thr. Wave w owns 16 q-rows. KV tile = 64.
// maskL = mask*log2e; softmax computed in exp2 domain (identical math).
__global__ __launch_bounds__(256) void attn_k(
    const bf16* __restrict__ Qb, const bf16* __restrict__ Kb, const bf16* __restrict__ Vt,
    const float* __restrict__ maskL, bf16* __restrict__ Ob) {
  constexpr int PPAD = 72;
  __shared__ short Ks[64 * 64];
  __shared__ short Vts[64 * 64];
  __shared__ float Ms[64 * 64];   // 16 KB mask tile (f32, log2e-scaled)
  __shared__ short Ps[4][16 * PPAD];
  const int tid = threadIdx.x;
  const int l = tid & 63, w = tid >> 6;
  const int b = blockIdx.z, h = blockIdx.y, q0 = blockIdx.x * 64;
  const int lr = l & 15, lg = l >> 4, lk = lg * 8;
  const int swz = lr & 7;

  const size_t qoff = (size_t)(b * NN + q0 + w * 16 + lr) * DD + h * 64;
  bf16x8s qf0 = *reinterpret_cast<const bf16x8s*>(Qb + qoff + lk);
  bf16x8s qf1 = *reinterpret_cast<const bf16x8s*>(Qb + qoff + 32 + lk);

  f32x4 acc[4] = {};
  float mrun[4], lrun[4];
#pragma unroll
  for (int r = 0; r < 4; r++) { mrun[r] = -1e30f; lrun[r] = 0.f; }

  const size_t kbase = (size_t)b * NN * DD + h * 64;
  const size_t vbase = (size_t)(b * HH + h) * 64 * NN;
  const int mrow0 = w * 16 + lg * 4;  // this wave's q rows within the 64-row tile

  for (int jt = 0; jt < NN; jt += 64) {
    __syncthreads();  // prior tile's readers done before overwrite
#pragma unroll
    for (int i = 0; i < 2; i++) {
      int c = i * 256 + tid;          // chunk 0..511
      int row = c >> 3, gch = (c & 7) ^ (row & 7);
      short* lbK = (short*)Ks + (size_t)(i * 256 + w * 64) * 8;  // wave-uniform dest
      GLOAD_LDS16(Kb + kbase + (size_t)(jt + row) * DD + gch * 8, lbK);
      short* lbV = (short*)Vts + (size_t)(i * 256 + w * 64) * 8;
      GLOAD_LDS16(Vt + vbase + (size_t)row * NN + jt + gch * 8, lbV);
    }
#pragma unroll
    for (int i = 0; i < 4; i++) {
      int c = i * 256 + tid;          // chunk 0..1023 (16 chunks per 64-f32 row)
      int row = c >> 4, c4 = (c & 15) * 4;
      float* lbM = Ms + (size_t)(i * 256 + w * 64) * 4;  // wave-uniform dest
      GLOAD_LDS16(maskL + (size_t)(q0 + row) * NN + jt + c4, lbM);
    }
    __syncthreads();

    // S = Q K^T  (16 q-rows x 64 j)
    f32x4 s[4];
#pragma unroll
    for (int jj = 0; jj < 4; jj++) {
      bf16x8s k0 = *reinterpret_cast<const bf16x8s*>(
          &Ks[(jj * 16 + lr) * 64 + ((0 + lg) ^ swz) * 8]);
      bf16x8s k1 = *reinterpret_cast<const bf16x8s*>(
          &Ks[(jj * 16 + lr) * 64 + ((4 + lg) ^ swz) * 8]);
      f32x4 z = {0.f, 0.f, 0.f, 0.f};
      z = __builtin_amdgcn_mfma_f32_16x16x32_bf16(qf0, k0, z, 0, 0, 0);
      s[jj] = __builtin_amdgcn_mfma_f32_16x16x32_bf16(qf1, k1, z, 0, 0, 0);
    }

    // logits (log2 domain): l = s * maskL   (mask from LDS)
    float lv[4][4];  // [jj][r]
#pragma unroll
    for (int jj = 0; jj < 4; jj++)
#pragma unroll
      for (int r = 0; r < 4; r++)
        lv[jj][r] = s[jj][r] * Ms[(mrow0 + r) * 64 + jj * 16 + lr];

    // row maxima (16-lane groups along lr)
    float mx4[4];
#pragma unroll
    for (int r = 0; r < 4; r++) {
      float mx = fmaxf(fmaxf(lv[0][r], lv[1][r]), fmaxf(lv[2][r], lv[3][r]));
#pragma unroll
      for (int off = 8; off >= 1; off >>= 1) mx = fmaxf(mx, __shfl_xor(mx, off, 64));
      mx4[r] = mx;
    }
    // defer-max: rescale only if some row grew by > 11 (log2 domain)
    bool need = (mx4[0] > mrun[0] + 11.0f) || (mx4[1] > mrun[1] + 11.0f) ||
                (mx4[2] > mrun[2] + 11.0f) || (mx4[3] > mrun[3] + 11.0f);
    if (__any(need)) {
#pragma unroll
      for (int r = 0; r < 4; r++) {
        float mnew = fmaxf(mrun[r], mx4[r]);
        float sc = __builtin_amdgcn_exp2f(mrun[r] - mnew);
        mrun[r] = mnew;
        lrun[r] *= sc;
#pragma unroll
        for (int s4 = 0; s4 < 4; s4++) acc[s4][r] *= sc;
      }
    }
    // P = exp2(l - m), row sums, pack to LDS (wave-private)
    short* Pw = &Ps[w][0];
#pragma unroll
    for (int r = 0; r < 4; r++) {
      float rs = 0.f;
#pragma unroll
      for (int jj = 0; jj < 4; jj++) {
        float p = __builtin_amdgcn_exp2f(lv[jj][r] - mrun[r]);
        bf16 pb = __float2bfloat16(p);
        Pw[(lg * 4 + r) * PPAD + jj * 16 + lr] = *reinterpret_cast<short*>(&pb);
        rs += p;
      }
#pragma unroll
      for (int off = 8; off >= 1; off >>= 1) rs += __shfl_xor(rs, off, 64);
      lrun[r] += rs;
    }
    // wave-private P: no barrier needed, just drain DS writes before reading
    asm volatile("s_waitcnt lgkmcnt(0)" ::: "memory");
    __builtin_amdgcn_sched_barrier(0);

    // O += P V
    bf16x8s pa0 = *reinterpret_cast<const bf16x8s*>(&Pw[lr * PPAD + lk]);
    bf16x8s pa1 = *reinterpret_cast<const bf16x8s*>(&Pw[lr * PPAD + 32 + lk]);
#pragma unroll
    for (int s4 = 0; s4 < 4; s4++) {
      bf16x8s v0 = *reinterpret_cast<const bf16x8s*>(
          &Vts[(s4 * 16 + lr) * 64 + ((0 + lg) ^ swz) * 8]);
      bf16x8s v1 = *reinterpret_cast<const bf16x8s*>(
          &Vts[(s4 * 16 + lr) * 64 + ((4 + lg) ^ swz) * 8]);
      acc[s4] = __builtin_amdgcn_mfma_f32_16x16x32_bf16(pa0, v0, acc[s4], 0, 0, 0);
      acc[s4] = __builtin_amdgcn_mfma_f32_16x16x32_bf16(pa1, v1, acc[s4], 0, 0, 0);
    }
  }

  // epilogue: normalize and store attention output (bf16)
#pragma unroll
  for (int s4 = 0; s4 < 4; s4++)
#pragma unroll
    for (int r = 0; r < 4; r++) {
      size_t row = (size_t)(b * NN + q0 + w * 16 + lg * 4 + r);
      float v = acc[s4][r] / lrun[r];
      Ob[row * DD + h * 64 + s4 * 16 + lr] = __float2bfloat16(v);
    }
}

// ---------------- orchestration ----------------
extern "C" void kernel_launch(void* const* d_in, const int* in_sizes, int n_in,
                              void* d_out, int out_size, void* d_ws, size_t ws_size,
                              hipStream_t stream) {
  (void)in_sizes; (void)n_in; (void)out_size; (void)ws_size;
  const float* x    = (const float*)d_in[0];
  const float* cg   = (const float*)d_in[1];
  const float* mask = (const float*)d_in[2];
  const float* Wq   = (const float*)d_in[3];
  const float* bq   = (const float*)d_in[4];
  const float* Wk   = (const float*)d_in[5];
  const float* bk   = (const float*)d_in[6];
  const float* Wc   = (const float*)d_in[7];
  const float* bc   = (const float*)d_in[8];
  const float* We   = (const float*)d_in[9];
  const float* be   = (const float*)d_in[10];
  const float* Wv   = (const float*)d_in[11];
  const float* bv   = (const float*)d_in[12];
  const float* Wo   = (const float*)d_in[13];
  const float* bo   = (const float*)d_in[14];

  auto MB = [](size_t m) { return m << 20; };
  char* ws = (char*)d_ws;
  bf16* xb   = (bf16*)(ws + MB(0));    // 16 MB
  bf16* WqT  = (bf16*)(ws + MB(16));   // 2 MB each
  bf16* WkT  = (bf16*)(ws + MB(18));
  bf16* WvT  = (bf16*)(ws + MB(20));
  bf16* WoT  = (bf16*)(ws + MB(22));
  float* cq  = (float*)(ws + MB(24));  // 8 MB f32 (dead after Q GEMM)
  float* ck  = (float*)(ws + MB(32));  // 8 MB f32 (dead after K GEMM)
  bf16* Qb   = (bf16*)(ws + MB(40));   // 16 MB
  bf16* Kb   = (bf16*)(ws + MB(56));   // 16 MB
  bf16* Vb   = (bf16*)(ws + MB(72));   // 16 MB (dead after transpose_v)
  bf16* Vt   = (bf16*)(ws + MB(88));   // 16 MB -> peak 104 MB
  bf16* Ob   = (bf16*)(ws + MB(72));   // overlays Vb (dead)
  float* maskL = (float*)(ws + MB(24)); // 16 MB, overlays cq/ck (dead)
  // overlays, dead after cq/ck GEMMs (before Qb/Kb are written):
  bf16* WcT  = (bf16*)(ws + MB(40));   // 4 MB
  bf16* WeT  = (bf16*)(ws + MB(44));   // 4 MB
  bf16* cgb  = (bf16*)(ws + MB(48));   // 8 MB
  bf16* cgT  = (bf16*)(ws + MB(56));   // 8 MB

  cast_f32_bf16<<<dim3(BB * NN * DD / 4 / 256), 256, 0, stream>>>(x, xb, BB * NN * DD);
  cast_f32_bf16<<<dim3(NN * NN / 4 / 256), 256, 0, stream>>>(cg, cgb, NN * NN);
  dim3 tb(32, 8);
  transpose_cast<<<dim3(DD / 32, DD / 32), tb, 0, stream>>>(Wq, WqT, DD, DD);
  transpose_cast<<<dim3(DD / 32, DD / 32), tb, 0, stream>>>(Wk, WkT, DD, DD);
  transpose_cast<<<dim3(DD / 32, DD / 32), tb, 0, stream>>>(Wv, WvT, DD, DD);
  transpose_cast<<<dim3(DD / 32, DD / 32), tb, 0, stream>>>(Wo, WoT, DD, DD);
  transpose_cast<<<dim3(DD / 32, NN / 32), tb, 0, stream>>>(Wc, WcT, NN, DD);
  transpose_cast<<<dim3(DD / 32, NN / 32), tb, 0, stream>>>(We, WeT, NN, DD);
  transpose_cast<<<dim3(NN / 32, NN / 32), tb, 0, stream>>>(cg, cgT, NN, NN);

  // cq = cg@Wc + bc ; ck = cg^T@We + be   (f32 out)
  gemm_bt<0, 0><<<dim3(DD / 128, NN / 128), 256, 0, stream>>>(cgb, WcT, cq, bc, nullptr, NN, DD, NN, 1.0f);
  gemm_bt<0, 0><<<dim3(DD / 128, NN / 128), 256, 0, stream>>>(cgT, WeT, ck, be, nullptr, NN, DD, NN, 1.0f);
  // Q = 0.125*(x@Wq + bq + cq[row]) ; K = x@Wk + bk + ck[row] ; V = x@Wv + bv   (bf16 out)
  gemm_bt<1, 1><<<dim3(DD / 128, BB * NN / 128), 256, 0, stream>>>(xb, WqT, Qb, bq, cq, BB * NN, DD, DD, 0.125f);
  gemm_bt<1, 1><<<dim3(DD / 128, BB * NN / 128), 256, 0, stream>>>(xb, WkT, Kb, bk, ck, BB * NN, DD, DD, 1.0f);
  gemm_bt<1, 0><<<dim3(DD / 128, BB * NN / 128), 256, 0, stream>>>(xb, WvT, Vb, bv, nullptr, BB * NN, DD, DD, 1.0f);

  // mask * log2e (cq/ck now dead)
  mask_prep<<<dim3(NN * NN / 4 / 256), 256, 0, stream>>>(mask, maskL, NN * NN);

  transpose_v<<<dim3(NN / 32, 2, BB * HH), tb, 0, stream>>>(Vb, Vt);

  attn_k<<<dim3(NN / 64, HH, BB), 256, 0, stream>>>(Qb, Kb, Vt, maskL, Ob);

  // out = attn@Wo + bo  (f32 out)
  gemm_bt<0, 0><<<dim3(DD / 128, BB * NN / 128), 256, 0, stream>>>(Ob, WoT, (float*)d_out, bo, nullptr, BB * NN, DD, DD, 1.0f);
}

// Round 5
// 452.033 us; speedup vs baseline: 1.0733x; 1.0733x over previous
//
#include <hip/hip_runtime.h>
#include <hip/hip_bf16.h>

#define BB 4
#define NN 2048
#define DD 1024
#define HH 16

using bf16 = __hip_bfloat16;
typedef __attribute__((ext_vector_type(8))) short bf16x8s;
typedef __attribute__((ext_vector_type(4))) float f32x4;

#define GLOAD_LDS16(gp, lp)                                                   \
  __builtin_amdgcn_global_load_lds(                                           \
      (const __attribute__((address_space(1))) void*)(gp),                    \
      (__attribute__((address_space(3))) void*)(lp), 16, 0, 0)

// ---------------- cast f32 -> bf16 (vectorized x4) ----------------
__global__ void cast_f32_bf16(const float* __restrict__ in, bf16* __restrict__ out, int n) {
  int i = (blockIdx.x * blockDim.x + threadIdx.x) * 4;
  if (i >= n) return;
  float4 v = *reinterpret_cast<const float4*>(in + i);
  ushort4 o;
  bf16 t0 = __float2bfloat16(v.x); o.x = *reinterpret_cast<unsigned short*>(&t0);
  bf16 t1 = __float2bfloat16(v.y); o.y = *reinterpret_cast<unsigned short*>(&t1);
  bf16 t2 = __float2bfloat16(v.z); o.z = *reinterpret_cast<unsigned short*>(&t2);
  bf16 t3 = __float2bfloat16(v.w); o.w = *reinterpret_cast<unsigned short*>(&t3);
  *reinterpret_cast<ushort4*>(out + i) = o;
}

// ---------------- transpose + cast: in[R,C] f32 -> out[C,R] bf16 ----------------
__global__ void transpose_cast(const float* __restrict__ in, bf16* __restrict__ out, int R, int C) {
  __shared__ float t[32][33];
  int c0 = blockIdx.x * 32, r0 = blockIdx.y * 32;
  int tx = threadIdx.x, ty = threadIdx.y;  // block (32,8)
#pragma unroll
  for (int i = 0; i < 4; i++)
    t[ty + i * 8][tx] = in[(size_t)(r0 + ty + i * 8) * C + c0 + tx];
  __syncthreads();
#pragma unroll
  for (int i = 0; i < 4; i++)
    out[(size_t)(c0 + ty + i * 8) * R + r0 + tx] = __float2bfloat16(t[tx][ty + i * 8]);
}

// ---------------- mask transpose + log2e scale: maskT[c][r] = mask[r][c]*log2e ----------------
__global__ void maskT_prep(const float* __restrict__ in, float* __restrict__ out) {
  __shared__ float t[32][33];
  int c0 = blockIdx.x * 32, r0 = blockIdx.y * 32;
  int tx = threadIdx.x, ty = threadIdx.y;  // block (32,8)
#pragma unroll
  for (int i = 0; i < 4; i++)
    t[ty + i * 8][tx] = in[(size_t)(r0 + ty + i * 8) * NN + c0 + tx];
  __syncthreads();
  const float c = 1.4426950408889634f;
#pragma unroll
  for (int i = 0; i < 4; i++)
    out[(size_t)(c0 + ty + i * 8) * NN + r0 + tx] = t[tx][ty + i * 8] * c;
}

// ---------------- bf16->bf16 transpose of V into per-head layout ----------------
// Vb [B*N][D] -> Vt [B*H][64][N]  (Vt[bh][d][n] = Vb[b*N+n][h*64+d])
__global__ void transpose_v(const bf16* __restrict__ Vb, bf16* __restrict__ Vt) {
  __shared__ short t[32][33];
  int bh = blockIdx.z; int b = bh >> 4, h = bh & 15;
  int n0 = blockIdx.x * 32, d0 = blockIdx.y * 32;
  int tx = threadIdx.x, ty = threadIdx.y;  // block (32,8)
#pragma unroll
  for (int i = 0; i < 4; i++)
    t[ty + i * 8][tx] = reinterpret_cast<const short*>(Vb)[
        (size_t)(b * NN + n0 + ty + i * 8) * DD + h * 64 + d0 + tx];
  __syncthreads();
#pragma unroll
  for (int i = 0; i < 4; i++)
    reinterpret_cast<short*>(Vt)[(size_t)(bh * 64 + d0 + ty + i * 8) * NN + n0 + tx] =
        t[tx][ty + i * 8];
}

// ---------------- bf16 MFMA GEMM: C[M,Nc] = scale*(A[M,K] * BT[Nc,K]^T + bias (+rowadd)) ----
// 128x128 tile, BK=64, 4 waves (2x2). global_load_lds width=16 into linear [128][64] LDS;
// XOR chunk-swizzle on global source + ds_read (rule #21).
template <int OUT_BF16, int HAS_ROWADD>
__global__ __launch_bounds__(256) void gemm_bt(
    const bf16* __restrict__ A, const bf16* __restrict__ BT, void* __restrict__ Cout,
    const float* __restrict__ bias, const float* __restrict__ rowadd,
    int M, int Nc, int K, float scale) {
  __shared__ short As[128 * 64];
  __shared__ short Bs[128 * 64];
  const int tid = threadIdx.x;
  const int l = tid & 63, w = tid >> 6;
  const int wr = (w >> 1) * 64, wc = (w & 1) * 64;
  const int brow = blockIdx.y * 128, bcol = blockIdx.x * 128;
  const int lr = l & 15, lg = l >> 4;
  const int swz = lr & 7;
  f32x4 acc[4][4] = {};
  for (int k0 = 0; k0 < K; k0 += 64) {
#pragma unroll
    for (int i = 0; i < 4; i++) {
      int c = i * 256 + tid;          // chunk index 0..1023 (16B chunks)
      int row = c >> 3, gch = (c & 7) ^ (row & 7);
      short* lA = (short*)As + (size_t)(i * 256 + w * 64) * 8;  // wave-uniform dest
      GLOAD_LDS16(A + (size_t)(brow + row) * K + k0 + gch * 8, lA);
      short* lB = (short*)Bs + (size_t)(i * 256 + w * 64) * 8;
      GLOAD_LDS16(BT + (size_t)(bcol + row) * K + k0 + gch * 8, lB);
    }
    __syncthreads();
#pragma unroll
    for (int t = 0; t < 2; t++) {
      bf16x8s a[4], bfr[4];
#pragma unroll
      for (int m = 0; m < 4; m++)
        a[m] = *reinterpret_cast<const bf16x8s*>(
            &As[(wr + m * 16 + lr) * 64 + ((t * 4 + lg) ^ swz) * 8]);
#pragma unroll
      for (int n = 0; n < 4; n++)
        bfr[n] = *reinterpret_cast<const bf16x8s*>(
            &Bs[(wc + n * 16 + lr) * 64 + ((t * 4 + lg) ^ swz) * 8]);
      __builtin_amdgcn_s_setprio(1);
#pragma unroll
      for (int m = 0; m < 4; m++)
#pragma unroll
        for (int n = 0; n < 4; n++)
          acc[m][n] = __builtin_amdgcn_mfma_f32_16x16x32_bf16(a[m], bfr[n], acc[m][n], 0, 0, 0);
      __builtin_amdgcn_s_setprio(0);
    }
    __syncthreads();
  }
#pragma unroll
  for (int m = 0; m < 4; m++) {
#pragma unroll
    for (int n = 0; n < 4; n++) {
      int col = bcol + wc + n * 16 + lr;
      float bv = bias[col];
#pragma unroll
      for (int r = 0; r < 4; r++) {
        int row = brow + wr + m * 16 + (l >> 4) * 4 + r;
        float v = acc[m][n][r] + bv;
        if (HAS_ROWADD) v += rowadd[(size_t)(row & (NN - 1)) * Nc + col];
        v *= scale;
        if (OUT_BF16)
          reinterpret_cast<bf16*>(Cout)[(size_t)row * Nc + col] = __float2bfloat16(v);
        else
          reinterpret_cast<float*>(Cout)[(size_t)row * Nc + col] = v;
      }
    }
  }
}

// ---------------- flash attention, exp2-domain, defer-max, transposed mask ----------------
// grid (N/64, H, B), 256 thr. Wave w owns 16 q-rows. KV tile = 64.
// maskT[c][r] = mask[r][c]*log2e; softmax in exp2 domain (identical math).
__global__ __launch_bounds__(256) void attn_k(
    const bf16* __restrict__ Qb, const bf16* __restrict__ Kb, const bf16* __restrict__ Vt,
    const float* __restrict__ maskT, bf16* __restrict__ Ob) {
  constexpr int PPAD = 72;
  __shared__ short Ks[64 * 64];
  __shared__ short Vts[64 * 64];
  __shared__ short Ps[4][16 * PPAD];
  const int tid = threadIdx.x;
  const int l = tid & 63, w = tid >> 6;
  const int b = blockIdx.z, h = blockIdx.y, q0 = blockIdx.x * 64;
  const int lr = l & 15, lg = l >> 4, lk = lg * 8;
  const int swz = lr & 7;

  const size_t qoff = (size_t)(b * NN + q0 + w * 16 + lr) * DD + h * 64;
  bf16x8s qf0 = *reinterpret_cast<const bf16x8s*>(Qb + qoff + lk);
  bf16x8s qf1 = *reinterpret_cast<const bf16x8s*>(Qb + qoff + 32 + lk);

  f32x4 acc[4] = {};
  float mrun[4], lrun[4];
#pragma unroll
  for (int r = 0; r < 4; r++) { mrun[r] = -1e30f; lrun[r] = 0.f; }

  const size_t kbase = (size_t)b * NN * DD + h * 64;
  const size_t vbase = (size_t)(b * HH + h) * 64 * NN;
  const int mrow = q0 + w * 16 + lg * 4;  // this lane's 4 consecutive q rows

  for (int jt = 0; jt < NN; jt += 64) {
    __syncthreads();  // prior tile's readers done before overwrite
#pragma unroll
    for (int i = 0; i < 2; i++) {
      int c = i * 256 + tid;          // chunk 0..511
      int row = c >> 3, gch = (c & 7) ^ (row & 7);
      short* lbK = (short*)Ks + (size_t)(i * 256 + w * 64) * 8;  // wave-uniform dest
      GLOAD_LDS16(Kb + kbase + (size_t)(jt + row) * DD + gch * 8, lbK);
      short* lbV = (short*)Vts + (size_t)(i * 256 + w * 64) * 8;
      GLOAD_LDS16(Vt + vbase + (size_t)row * NN + jt + gch * 8, lbV);
    }
    __syncthreads();

    // S = Q K^T  (16 q-rows x 64 j)
    f32x4 s[4];
#pragma unroll
    for (int jj = 0; jj < 4; jj++) {
      bf16x8s k0 = *reinterpret_cast<const bf16x8s*>(
          &Ks[(jj * 16 + lr) * 64 + ((0 + lg) ^ swz) * 8]);
      bf16x8s k1 = *reinterpret_cast<const bf16x8s*>(
          &Ks[(jj * 16 + lr) * 64 + ((4 + lg) ^ swz) * 8]);
      f32x4 z = {0.f, 0.f, 0.f, 0.f};
      __builtin_amdgcn_s_setprio(1);
      z = __builtin_amdgcn_mfma_f32_16x16x32_bf16(qf0, k0, z, 0, 0, 0);
      s[jj] = __builtin_amdgcn_mfma_f32_16x16x32_bf16(qf1, k1, z, 0, 0, 0);
      __builtin_amdgcn_s_setprio(0);
    }

    // logits (log2 domain): lane's 4 rows are consecutive -> float4 mask load
    float lv[4][4];  // [jj][r]
#pragma unroll
    for (int jj = 0; jj < 4; jj++) {
      float4 mv = *reinterpret_cast<const float4*>(
          maskT + (size_t)(jt + jj * 16 + lr) * NN + mrow);
      lv[jj][0] = s[jj][0] * mv.x;
      lv[jj][1] = s[jj][1] * mv.y;
      lv[jj][2] = s[jj][2] * mv.z;
      lv[jj][3] = s[jj][3] * mv.w;
    }

    // row maxima (16-lane groups along lr)
    float mx4[4];
#pragma unroll
    for (int r = 0; r < 4; r++) {
      float mx = fmaxf(fmaxf(lv[0][r], lv[1][r]), fmaxf(lv[2][r], lv[3][r]));
#pragma unroll
      for (int off = 8; off >= 1; off >>= 1) mx = fmaxf(mx, __shfl_xor(mx, off, 64));
      mx4[r] = mx;
    }
    // defer-max: rescale only if some row grew by > 11 (log2 domain)
    bool need = (mx4[0] > mrun[0] + 11.0f) || (mx4[1] > mrun[1] + 11.0f) ||
                (mx4[2] > mrun[2] + 11.0f) || (mx4[3] > mrun[3] + 11.0f);
    if (__any(need)) {
#pragma unroll
      for (int r = 0; r < 4; r++) {
        float mnew = fmaxf(mrun[r], mx4[r]);
        float sc = __builtin_amdgcn_exp2f(mrun[r] - mnew);
        mrun[r] = mnew;
        lrun[r] *= sc;
#pragma unroll
        for (int s4 = 0; s4 < 4; s4++) acc[s4][r] *= sc;
      }
    }
    // P = exp2(l - m), row sums, pack to LDS (wave-private)
    short* Pw = &Ps[w][0];
#pragma unroll
    for (int r = 0; r < 4; r++) {
      float rs = 0.f;
#pragma unroll
      for (int jj = 0; jj < 4; jj++) {
        float p = __builtin_amdgcn_exp2f(lv[jj][r] - mrun[r]);
        bf16 pb = __float2bfloat16(p);
        Pw[(lg * 4 + r) * PPAD + jj * 16 + lr] = *reinterpret_cast<short*>(&pb);
        rs += p;
      }
#pragma unroll
      for (int off = 8; off >= 1; off >>= 1) rs += __shfl_xor(rs, off, 64);
      lrun[r] += rs;
    }
    // wave-private P: no barrier needed, just drain DS writes before reading
    asm volatile("s_waitcnt lgkmcnt(0)" ::: "memory");
    __builtin_amdgcn_sched_barrier(0);

    // O += P V
    bf16x8s pa0 = *reinterpret_cast<const bf16x8s*>(&Pw[lr * PPAD + lk]);
    bf16x8s pa1 = *reinterpret_cast<const bf16x8s*>(&Pw[lr * PPAD + 32 + lk]);
#pragma unroll
    for (int s4 = 0; s4 < 4; s4++) {
      bf16x8s v0 = *reinterpret_cast<const bf16x8s*>(
          &Vts[(s4 * 16 + lr) * 64 + ((0 + lg) ^ swz) * 8]);
      bf16x8s v1 = *reinterpret_cast<const bf16x8s*>(
          &Vts[(s4 * 16 + lr) * 64 + ((4 + lg) ^ swz) * 8]);
      __builtin_amdgcn_s_setprio(1);
      acc[s4] = __builtin_amdgcn_mfma_f32_16x16x32_bf16(pa0, v0, acc[s4], 0, 0, 0);
      acc[s4] = __builtin_amdgcn_mfma_f32_16x16x32_bf16(pa1, v1, acc[s4], 0, 0, 0);
      __builtin_amdgcn_s_setprio(0);
    }
  }

  // epilogue: normalize (rcp) and store attention output (bf16)
  float rl[4];
#pragma unroll
  for (int r = 0; r < 4; r++) rl[r] = __builtin_amdgcn_rcpf(lrun[r]);
#pragma unroll
  for (int s4 = 0; s4 < 4; s4++)
#pragma unroll
    for (int r = 0; r < 4; r++) {
      size_t row = (size_t)(b * NN + q0 + w * 16 + lg * 4 + r);
      float v = acc[s4][r] * rl[r];
      Ob[row * DD + h * 64 + s4 * 16 + lr] = __float2bfloat16(v);
    }
}

// ---------------- orchestration ----------------
extern "C" void kernel_launch(void* const* d_in, const int* in_sizes, int n_in,
                              void* d_out, int out_size, void* d_ws, size_t ws_size,
                              hipStream_t stream) {
  (void)in_sizes; (void)n_in; (void)out_size; (void)ws_size;
  const float* x    = (const float*)d_in[0];
  const float* cg   = (const float*)d_in[1];
  const float* mask = (const float*)d_in[2];
  const float* Wq   = (const float*)d_in[3];
  const float* bq   = (const float*)d_in[4];
  const float* Wk   = (const float*)d_in[5];
  const float* bk   = (const float*)d_in[6];
  const float* Wc   = (const float*)d_in[7];
  const float* bc   = (const float*)d_in[8];
  const float* We   = (const float*)d_in[9];
  const float* be   = (const float*)d_in[10];
  const float* Wv   = (const float*)d_in[11];
  const float* bv   = (const float*)d_in[12];
  const float* Wo   = (const float*)d_in[13];
  const float* bo   = (const float*)d_in[14];

  auto MB = [](size_t m) { return m << 20; };
  char* ws = (char*)d_ws;
  bf16* xb   = (bf16*)(ws + MB(0));    // 16 MB
  bf16* WqT  = (bf16*)(ws + MB(16));   // 2 MB each
  bf16* WkT  = (bf16*)(ws + MB(18));
  bf16* WvT  = (bf16*)(ws + MB(20));
  bf16* WoT  = (bf16*)(ws + MB(22));
  float* cq  = (float*)(ws + MB(24));  // 8 MB f32 (dead after Q GEMM)
  float* ck  = (float*)(ws + MB(32));  // 8 MB f32 (dead after K GEMM)
  bf16* Qb   = (bf16*)(ws + MB(40));   // 16 MB
  bf16* Kb   = (bf16*)(ws + MB(56));   // 16 MB
  bf16* Vb   = (bf16*)(ws + MB(72));   // 16 MB (dead after transpose_v)
  bf16* Vt   = (bf16*)(ws + MB(88));   // 16 MB -> peak 104 MB
  bf16* Ob   = (bf16*)(ws + MB(72));   // overlays Vb (dead)
  float* maskT = (float*)(ws + MB(24)); // 16 MB, overlays cq/ck (dead)
  // overlays, dead after cq/ck GEMMs (before Qb/Kb are written):
  bf16* WcT  = (bf16*)(ws + MB(40));   // 4 MB
  bf16* WeT  = (bf16*)(ws + MB(44));   // 4 MB
  bf16* cgb  = (bf16*)(ws + MB(48));   // 8 MB
  bf16* cgT  = (bf16*)(ws + MB(56));   // 8 MB

  cast_f32_bf16<<<dim3(BB * NN * DD / 4 / 256), 256, 0, stream>>>(x, xb, BB * NN * DD);
  cast_f32_bf16<<<dim3(NN * NN / 4 / 256), 256, 0, stream>>>(cg, cgb, NN * NN);
  dim3 tb(32, 8);
  transpose_cast<<<dim3(DD / 32, DD / 32), tb, 0, stream>>>(Wq, WqT, DD, DD);
  transpose_cast<<<dim3(DD / 32, DD / 32), tb, 0, stream>>>(Wk, WkT, DD, DD);
  transpose_cast<<<dim3(DD / 32, DD / 32), tb, 0, stream>>>(Wv, WvT, DD, DD);
  transpose_cast<<<dim3(DD / 32, DD / 32), tb, 0, stream>>>(Wo, WoT, DD, DD);
  transpose_cast<<<dim3(DD / 32, NN / 32), tb, 0, stream>>>(Wc, WcT, NN, DD);
  transpose_cast<<<dim3(DD / 32, NN / 32), tb, 0, stream>>>(We, WeT, NN, DD);
  transpose_cast<<<dim3(NN / 32, NN / 32), tb, 0, stream>>>(cg, cgT, NN, NN);

  // cq = cg@Wc + bc ; ck = cg^T@We + be   (f32 out)
  gemm_bt<0, 0><<<dim3(DD / 128, NN / 128), 256, 0, stream>>>(cgb, WcT, cq, bc, nullptr, NN, DD, NN, 1.0f);
  gemm_bt<0, 0><<<dim3(DD / 128, NN / 128), 256, 0, stream>>>(cgT, WeT, ck, be, nullptr, NN, DD, NN, 1.0f);
  // Q = 0.125*(x@Wq + bq + cq[row]) ; K = x@Wk + bk + ck[row] ; V = x@Wv + bv   (bf16 out)
  gemm_bt<1, 1><<<dim3(DD / 128, BB * NN / 128), 256, 0, stream>>>(xb, WqT, Qb, bq, cq, BB * NN, DD, DD, 0.125f);
  gemm_bt<1, 1><<<dim3(DD / 128, BB * NN / 128), 256, 0, stream>>>(xb, WkT, Kb, bk, ck, BB * NN, DD, DD, 1.0f);
  gemm_bt<1, 0><<<dim3(DD / 128, BB * NN / 128), 256, 0, stream>>>(xb, WvT, Vb, bv, nullptr, BB * NN, DD, DD, 1.0f);

  // maskT = transpose(mask) * log2e   (cq/ck now dead)
  maskT_prep<<<dim3(NN / 32, NN / 32), tb, 0, stream>>>(mask, maskT);

  transpose_v<<<dim3(NN / 32, 2, BB * HH), tb, 0, stream>>>(Vb, Vt);

  attn_k<<<dim3(NN / 64, HH, BB), 256, 0, stream>>>(Qb, Kb, Vt, maskT, Ob);

  // out = attn@Wo + bo  (f32 out)
  gemm_bt<0, 0><<<dim3(DD / 128, BB * NN / 128), 256, 0, stream>>>(Ob, WoT, (float*)d_out, bo, nullptr, BB * NN, DD, DD, 1.0f);
}

// Round 6
// 403.319 us; speedup vs baseline: 1.2029x; 1.1208x over previous
//
#include <hip/hip_runtime.h>
#include <hip/hip_bf16.h>

#define BB 4
#define NN 2048
#define DD 1024
#define HH 16

using bf16 = __hip_bfloat16;
typedef __attribute__((ext_vector_type(8))) short bf16x8s;
typedef __attribute__((ext_vector_type(4))) float f32x4;

#define GLOAD_LDS16(gp, lp)                                                   \
  __builtin_amdgcn_global_load_lds(                                           \
      (const __attribute__((address_space(1))) void*)(gp),                    \
      (__attribute__((address_space(3))) void*)(lp), 16, 0, 0)

// ---------------- cast f32 -> bf16 (vectorized x4) ----------------
__global__ void cast_f32_bf16(const float* __restrict__ in, bf16* __restrict__ out, int n) {
  int i = (blockIdx.x * blockDim.x + threadIdx.x) * 4;
  if (i >= n) return;
  float4 v = *reinterpret_cast<const float4*>(in + i);
  ushort4 o;
  bf16 t0 = __float2bfloat16(v.x); o.x = *reinterpret_cast<unsigned short*>(&t0);
  bf16 t1 = __float2bfloat16(v.y); o.y = *reinterpret_cast<unsigned short*>(&t1);
  bf16 t2 = __float2bfloat16(v.z); o.z = *reinterpret_cast<unsigned short*>(&t2);
  bf16 t3 = __float2bfloat16(v.w); o.w = *reinterpret_cast<unsigned short*>(&t3);
  *reinterpret_cast<ushort4*>(out + i) = o;
}

// ---------------- mask prep: maskL = mask * log2(e)  (exp2-domain softmax) ----------------
__global__ void mask_prep(const float* __restrict__ in, float* __restrict__ out, int n) {
  int i = (blockIdx.x * blockDim.x + threadIdx.x) * 4;
  if (i >= n) return;
  float4 v = *reinterpret_cast<const float4*>(in + i);
  const float c = 1.4426950408889634f;
  v.x *= c; v.y *= c; v.z *= c; v.w *= c;
  *reinterpret_cast<float4*>(out + i) = v;
}

// ---------------- transpose + cast: in[R,C] f32 -> out[C,R] bf16 ----------------
__global__ void transpose_cast(const float* __restrict__ in, bf16* __restrict__ out, int R, int C) {
  __shared__ float t[32][33];
  int c0 = blockIdx.x * 32, r0 = blockIdx.y * 32;
  int tx = threadIdx.x, ty = threadIdx.y;  // block (32,8)
#pragma unroll
  for (int i = 0; i < 4; i++)
    t[ty + i * 8][tx] = in[(size_t)(r0 + ty + i * 8) * C + c0 + tx];
  __syncthreads();
#pragma unroll
  for (int i = 0; i < 4; i++)
    out[(size_t)(c0 + ty + i * 8) * R + r0 + tx] = __float2bfloat16(t[tx][ty + i * 8]);
}

// ---------------- bf16->bf16 transpose of V into per-head layout ----------------
// Vb [B*N][D] -> Vt [B*H][64][N]  (Vt[bh][d][n] = Vb[b*N+n][h*64+d])
__global__ void transpose_v(const bf16* __restrict__ Vb, bf16* __restrict__ Vt) {
  __shared__ short t[32][33];
  int bh = blockIdx.z; int b = bh >> 4, h = bh & 15;
  int n0 = blockIdx.x * 32, d0 = blockIdx.y * 32;
  int tx = threadIdx.x, ty = threadIdx.y;  // block (32,8)
#pragma unroll
  for (int i = 0; i < 4; i++)
    t[ty + i * 8][tx] = reinterpret_cast<const short*>(Vb)[
        (size_t)(b * NN + n0 + ty + i * 8) * DD + h * 64 + d0 + tx];
  __syncthreads();
#pragma unroll
  for (int i = 0; i < 4; i++)
    reinterpret_cast<short*>(Vt)[(size_t)(bh * 64 + d0 + ty + i * 8) * NN + n0 + tx] =
        t[tx][ty + i * 8];
}

// ---------------- bf16 MFMA GEMM: C[M,Nc] = scale*(A[M,K] * BT[Nc,K]^T + bias (+rowadd)) ----
// 128x128 tile, BK=64, 4 waves (2x2). global_load_lds width=16 into linear [128][64] LDS;
// XOR chunk-swizzle on global source + ds_read (rule #21).
template <int OUT_BF16, int HAS_ROWADD>
__global__ __launch_bounds__(256) void gemm_bt(
    const bf16* __restrict__ A, const bf16* __restrict__ BT, void* __restrict__ Cout,
    const float* __restrict__ bias, const float* __restrict__ rowadd,
    int M, int Nc, int K, float scale) {
  __shared__ short As[128 * 64];
  __shared__ short Bs[128 * 64];
  const int tid = threadIdx.x;
  const int l = tid & 63, w = tid >> 6;
  const int wr = (w >> 1) * 64, wc = (w & 1) * 64;
  const int brow = blockIdx.y * 128, bcol = blockIdx.x * 128;
  const int lr = l & 15, lg = l >> 4;
  const int swz = lr & 7;
  f32x4 acc[4][4] = {};
  for (int k0 = 0; k0 < K; k0 += 64) {
#pragma unroll
    for (int i = 0; i < 4; i++) {
      int c = i * 256 + tid;          // chunk index 0..1023 (16B chunks)
      int row = c >> 3, gch = (c & 7) ^ (row & 7);
      short* lA = (short*)As + (size_t)(i * 256 + w * 64) * 8;  // wave-uniform dest
      GLOAD_LDS16(A + (size_t)(brow + row) * K + k0 + gch * 8, lA);
      short* lB = (short*)Bs + (size_t)(i * 256 + w * 64) * 8;
      GLOAD_LDS16(BT + (size_t)(bcol + row) * K + k0 + gch * 8, lB);
    }
    __syncthreads();
#pragma unroll
    for (int t = 0; t < 2; t++) {
      bf16x8s a[4], bfr[4];
#pragma unroll
      for (int m = 0; m < 4; m++)
        a[m] = *reinterpret_cast<const bf16x8s*>(
            &As[(wr + m * 16 + lr) * 64 + ((t * 4 + lg) ^ swz) * 8]);
#pragma unroll
      for (int n = 0; n < 4; n++)
        bfr[n] = *reinterpret_cast<const bf16x8s*>(
            &Bs[(wc + n * 16 + lr) * 64 + ((t * 4 + lg) ^ swz) * 8]);
#pragma unroll
      for (int m = 0; m < 4; m++)
#pragma unroll
        for (int n = 0; n < 4; n++)
          acc[m][n] = __builtin_amdgcn_mfma_f32_16x16x32_bf16(a[m], bfr[n], acc[m][n], 0, 0, 0);
    }
    __syncthreads();
  }
#pragma unroll
  for (int m = 0; m < 4; m++) {
#pragma unroll
    for (int n = 0; n < 4; n++) {
      int col = bcol + wc + n * 16 + lr;
      float bv = bias[col];
#pragma unroll
      for (int r = 0; r < 4; r++) {
        int row = brow + wr + m * 16 + (l >> 4) * 4 + r;
        float v = acc[m][n][r] + bv;
        if (HAS_ROWADD) v += rowadd[(size_t)(row & (NN - 1)) * Nc + col];
        v *= scale;
        if (OUT_BF16)
          reinterpret_cast<bf16*>(Cout)[(size_t)row * Nc + col] = __float2bfloat16(v);
        else
          reinterpret_cast<float*>(Cout)[(size_t)row * Nc + col] = v;
      }
    }
  }
}

// ---------------- flash attention, swapped-operand QK^T (q = lane&15) ----------------
// grid (N/64, H, B), 256 thr. Wave w owns 16 q-rows. KV tile = 64.
// mfma(K,Q) puts kv on the reg axis and q on lane&15: each lane owns one q-row's
// 16 kv values -> in-lane row reduce (15 ops + 2 shfl), scalar m/l state, b64 P writes.
// maskL = mask*log2e (row-major); softmax in exp2 domain.
__global__ __launch_bounds__(256) void attn_k(
    const bf16* __restrict__ Qb, const bf16* __restrict__ Kb, const bf16* __restrict__ Vt,
    const float* __restrict__ maskL, bf16* __restrict__ Ob) {
  constexpr int PPAD = 72;
  __shared__ short Ks[64 * 64];
  __shared__ short Vts[64 * 64];
  __shared__ short Ps[4][16 * PPAD];
  const int tid = threadIdx.x;
  const int l = tid & 63, w = tid >> 6;
  const int b = blockIdx.z, h = blockIdx.y, q0 = blockIdx.x * 64;
  const int lr = l & 15, lg = l >> 4, lk = lg * 8;
  const int swz = lr & 7;

  // Q fragment: lane holds Q-row q = lr, k-chunk lg*8 (+32)  [B-operand of mfma(K,Q)]
  const size_t qoff = (size_t)(b * NN + q0 + w * 16 + lr) * DD + h * 64;
  bf16x8s qf0 = *reinterpret_cast<const bf16x8s*>(Qb + qoff + lk);
  bf16x8s qf1 = *reinterpret_cast<const bf16x8s*>(Qb + qoff + 32 + lk);

  f32x4 acc[4] = {};          // O^T: col q=lr, row d = s4*16 + lg*4 + r
  float mrun = -1e30f, lrun = 0.f;  // per-lane scalars (q = lr)

  const size_t kbase = (size_t)b * NN * DD + h * 64;
  const size_t vbase = (size_t)(b * HH + h) * 64 * NN;
  const float* mptr = maskL + (size_t)(q0 + w * 16 + lr) * NN;  // this lane's q-row

  for (int jt = 0; jt < NN; jt += 64) {
    __syncthreads();  // prior tile's readers done before overwrite
#pragma unroll
    for (int i = 0; i < 2; i++) {
      int c = i * 256 + tid;          // chunk 0..511
      int row = c >> 3, gch = (c & 7) ^ (row & 7);
      short* lbK = (short*)Ks + (size_t)(i * 256 + w * 64) * 8;  // wave-uniform dest
      GLOAD_LDS16(Kb + kbase + (size_t)(jt + row) * DD + gch * 8, lbK);
      short* lbV = (short*)Vts + (size_t)(i * 256 + w * 64) * 8;
      GLOAD_LDS16(Vt + vbase + (size_t)row * NN + jt + gch * 8, lbV);
    }
    __syncthreads();

    // S^T = K Q^T: s[jj][r] = S[kv = jt + jj*16 + lg*4 + r][q = lr]
    f32x4 s[4];
#pragma unroll
    for (int jj = 0; jj < 4; jj++) {
      bf16x8s k0 = *reinterpret_cast<const bf16x8s*>(
          &Ks[(jj * 16 + lr) * 64 + ((0 + lg) ^ swz) * 8]);
      bf16x8s k1 = *reinterpret_cast<const bf16x8s*>(
          &Ks[(jj * 16 + lr) * 64 + ((4 + lg) ^ swz) * 8]);
      f32x4 z = {0.f, 0.f, 0.f, 0.f};
      z = __builtin_amdgcn_mfma_f32_16x16x32_bf16(k0, qf0, z, 0, 0, 0);
      s[jj] = __builtin_amdgcn_mfma_f32_16x16x32_bf16(k1, qf1, z, 0, 0, 0);
    }

    // logits (log2 domain), mask row-major float4 (4 consecutive kv per reg quad)
    float lv[4][4];
#pragma unroll
    for (int jj = 0; jj < 4; jj++) {
      float4 mv = *reinterpret_cast<const float4*>(mptr + jt + jj * 16 + lg * 4);
      lv[jj][0] = s[jj][0] * mv.x;
      lv[jj][1] = s[jj][1] * mv.y;
      lv[jj][2] = s[jj][2] * mv.z;
      lv[jj][3] = s[jj][3] * mv.w;
    }

    // full row max for q=lr: 15 in-lane fmax + 2 cross-group shuffles
    float mx0 = fmaxf(fmaxf(lv[0][0], lv[0][1]), fmaxf(lv[0][2], lv[0][3]));
    float mx1 = fmaxf(fmaxf(lv[1][0], lv[1][1]), fmaxf(lv[1][2], lv[1][3]));
    float mx2 = fmaxf(fmaxf(lv[2][0], lv[2][1]), fmaxf(lv[2][2], lv[2][3]));
    float mx3 = fmaxf(fmaxf(lv[3][0], lv[3][1]), fmaxf(lv[3][2], lv[3][3]));
    float mx = fmaxf(fmaxf(mx0, mx1), fmaxf(mx2, mx3));
    mx = fmaxf(mx, __shfl_xor(mx, 16, 64));
    mx = fmaxf(mx, __shfl_xor(mx, 32, 64));

    // defer-max: rescale only if this row grew by > 11 (log2 domain)
    if (__any(mx > mrun + 11.0f)) {
      float mnew = fmaxf(mrun, mx);
      float sc = __builtin_amdgcn_exp2f(mrun - mnew);
      mrun = mnew;
      lrun *= sc;
#pragma unroll
      for (int s4 = 0; s4 < 4; s4++)
#pragma unroll
        for (int r = 0; r < 4; r++) acc[s4][r] *= sc;
    }

    // P = exp2(lv - m): 16 values, pack 4 bf16 per jj -> one ds_write_b64 each
    short* Pw = &Ps[w][0];
    float rs = 0.f;
#pragma unroll
    for (int jj = 0; jj < 4; jj++) {
      float p0 = __builtin_amdgcn_exp2f(lv[jj][0] - mrun);
      float p1 = __builtin_amdgcn_exp2f(lv[jj][1] - mrun);
      float p2 = __builtin_amdgcn_exp2f(lv[jj][2] - mrun);
      float p3 = __builtin_amdgcn_exp2f(lv[jj][3] - mrun);
      rs += (p0 + p1) + (p2 + p3);
      ushort4 pk;
      bf16 b0 = __float2bfloat16(p0); pk.x = *reinterpret_cast<unsigned short*>(&b0);
      bf16 b1 = __float2bfloat16(p1); pk.y = *reinterpret_cast<unsigned short*>(&b1);
      bf16 b2 = __float2bfloat16(p2); pk.z = *reinterpret_cast<unsigned short*>(&b2);
      bf16 b3 = __float2bfloat16(p3); pk.w = *reinterpret_cast<unsigned short*>(&b3);
      *reinterpret_cast<ushort4*>(&Pw[lr * PPAD + jj * 16 + lg * 4]) = pk;
    }
    rs += __shfl_xor(rs, 16, 64);
    rs += __shfl_xor(rs, 32, 64);
    lrun += rs;

    // wave-private P: drain DS writes, fence the scheduler, no block barrier
    asm volatile("s_waitcnt lgkmcnt(0)" ::: "memory");
    __builtin_amdgcn_sched_barrier(0);

    // O^T += V^T P^T : A = V^T rows d, B = P rows q (lane lr)
    bf16x8s pb0 = *reinterpret_cast<const bf16x8s*>(&Pw[lr * PPAD + lk]);
    bf16x8s pb1 = *reinterpret_cast<const bf16x8s*>(&Pw[lr * PPAD + 32 + lk]);
#pragma unroll
    for (int s4 = 0; s4 < 4; s4++) {
      bf16x8s v0 = *reinterpret_cast<const bf16x8s*>(
          &Vts[(s4 * 16 + lr) * 64 + ((0 + lg) ^ swz) * 8]);
      bf16x8s v1 = *reinterpret_cast<const bf16x8s*>(
          &Vts[(s4 * 16 + lr) * 64 + ((4 + lg) ^ swz) * 8]);
      acc[s4] = __builtin_amdgcn_mfma_f32_16x16x32_bf16(v0, pb0, acc[s4], 0, 0, 0);
      acc[s4] = __builtin_amdgcn_mfma_f32_16x16x32_bf16(v1, pb1, acc[s4], 0, 0, 0);
    }
  }

  // epilogue: normalize (1 rcp/lane), pack 4 consecutive d per s4 -> 8B stores
  float rl = __builtin_amdgcn_rcpf(lrun);
  const size_t orow = (size_t)(b * NN + q0 + w * 16 + lr) * DD + h * 64;
#pragma unroll
  for (int s4 = 0; s4 < 4; s4++) {
    ushort4 o;
    bf16 b0 = __float2bfloat16(acc[s4][0] * rl); o.x = *reinterpret_cast<unsigned short*>(&b0);
    bf16 b1 = __float2bfloat16(acc[s4][1] * rl); o.y = *reinterpret_cast<unsigned short*>(&b1);
    bf16 b2 = __float2bfloat16(acc[s4][2] * rl); o.z = *reinterpret_cast<unsigned short*>(&b2);
    bf16 b3 = __float2bfloat16(acc[s4][3] * rl); o.w = *reinterpret_cast<unsigned short*>(&b3);
    *reinterpret_cast<ushort4*>(reinterpret_cast<unsigned short*>(Ob) + orow + s4 * 16 + lg * 4) = o;
  }
}

// ---------------- orchestration ----------------
extern "C" void kernel_launch(void* const* d_in, const int* in_sizes, int n_in,
                              void* d_out, int out_size, void* d_ws, size_t ws_size,
                              hipStream_t stream) {
  (void)in_sizes; (void)n_in; (void)out_size; (void)ws_size;
  const float* x    = (const float*)d_in[0];
  const float* cg   = (const float*)d_in[1];
  const float* mask = (const float*)d_in[2];
  const float* Wq   = (const float*)d_in[3];
  const float* bq   = (const float*)d_in[4];
  const float* Wk   = (const float*)d_in[5];
  const float* bk   = (const float*)d_in[6];
  const float* Wc   = (const float*)d_in[7];
  const float* bc   = (const float*)d_in[8];
  const float* We   = (const float*)d_in[9];
  const float* be   = (const float*)d_in[10];
  const float* Wv   = (const float*)d_in[11];
  const float* bv   = (const float*)d_in[12];
  const float* Wo   = (const float*)d_in[13];
  const float* bo   = (const float*)d_in[14];

  auto MB = [](size_t m) { return m << 20; };
  char* ws = (char*)d_ws;
  bf16* xb   = (bf16*)(ws + MB(0));    // 16 MB
  bf16* WqT  = (bf16*)(ws + MB(16));   // 2 MB each
  bf16* WkT  = (bf16*)(ws + MB(18));
  bf16* WvT  = (bf16*)(ws + MB(20));
  bf16* WoT  = (bf16*)(ws + MB(22));
  float* cq  = (float*)(ws + MB(24));  // 8 MB f32 (dead after Q GEMM)
  float* ck  = (float*)(ws + MB(32));  // 8 MB f32 (dead after K GEMM)
  bf16* Qb   = (bf16*)(ws + MB(40));   // 16 MB
  bf16* Kb   = (bf16*)(ws + MB(56));   // 16 MB
  bf16* Vb   = (bf16*)(ws + MB(72));   // 16 MB (dead after transpose_v)
  bf16* Vt   = (bf16*)(ws + MB(88));   // 16 MB -> peak 104 MB
  bf16* Ob   = (bf16*)(ws + MB(72));   // overlays Vb (dead)
  float* maskL = (float*)(ws + MB(24)); // 16 MB, overlays cq/ck (dead)
  // overlays, dead after cq/ck GEMMs (before Qb/Kb are written):
  bf16* WcT  = (bf16*)(ws + MB(40));   // 4 MB
  bf16* WeT  = (bf16*)(ws + MB(44));   // 4 MB
  bf16* cgb  = (bf16*)(ws + MB(48));   // 8 MB
  bf16* cgT  = (bf16*)(ws + MB(56));   // 8 MB

  cast_f32_bf16<<<dim3(BB * NN * DD / 4 / 256), 256, 0, stream>>>(x, xb, BB * NN * DD);
  cast_f32_bf16<<<dim3(NN * NN / 4 / 256), 256, 0, stream>>>(cg, cgb, NN * NN);
  dim3 tb(32, 8);
  transpose_cast<<<dim3(DD / 32, DD / 32), tb, 0, stream>>>(Wq, WqT, DD, DD);
  transpose_cast<<<dim3(DD / 32, DD / 32), tb, 0, stream>>>(Wk, WkT, DD, DD);
  transpose_cast<<<dim3(DD / 32, DD / 32), tb, 0, stream>>>(Wv, WvT, DD, DD);
  transpose_cast<<<dim3(DD / 32, DD / 32), tb, 0, stream>>>(Wo, WoT, DD, DD);
  transpose_cast<<<dim3(DD / 32, NN / 32), tb, 0, stream>>>(Wc, WcT, NN, DD);
  transpose_cast<<<dim3(DD / 32, NN / 32), tb, 0, stream>>>(We, WeT, NN, DD);
  transpose_cast<<<dim3(NN / 32, NN / 32), tb, 0, stream>>>(cg, cgT, NN, NN);

  // cq = cg@Wc + bc ; ck = cg^T@We + be   (f32 out)
  gemm_bt<0, 0><<<dim3(DD / 128, NN / 128), 256, 0, stream>>>(cgb, WcT, cq, bc, nullptr, NN, DD, NN, 1.0f);
  gemm_bt<0, 0><<<dim3(DD / 128, NN / 128), 256, 0, stream>>>(cgT, WeT, ck, be, nullptr, NN, DD, NN, 1.0f);
  // Q = 0.125*(x@Wq + bq + cq[row]) ; K = x@Wk + bk + ck[row] ; V = x@Wv + bv   (bf16 out)
  gemm_bt<1, 1><<<dim3(DD / 128, BB * NN / 128), 256, 0, stream>>>(xb, WqT, Qb, bq, cq, BB * NN, DD, DD, 0.125f);
  gemm_bt<1, 1><<<dim3(DD / 128, BB * NN / 128), 256, 0, stream>>>(xb, WkT, Kb, bk, ck, BB * NN, DD, DD, 1.0f);
  gemm_bt<1, 0><<<dim3(DD / 128, BB * NN / 128), 256, 0, stream>>>(xb, WvT, Vb, bv, nullptr, BB * NN, DD, DD, 1.0f);

  // maskL = mask * log2e (elementwise; cq/ck now dead)
  mask_prep<<<dim3(NN * NN / 4 / 256), 256, 0, stream>>>(mask, maskL, NN * NN);

  transpose_v<<<dim3(NN / 32, 2, BB * HH), tb, 0, stream>>>(Vb, Vt);

  attn_k<<<dim3(NN / 64, HH, BB), 256, 0, stream>>>(Qb, Kb, Vt, maskL, Ob);

  // out = attn@Wo + bo  (f32 out)
  gemm_bt<0, 0><<<dim3(DD / 128, BB * NN / 128), 256, 0, stream>>>(Ob, WoT, (float*)d_out, bo, nullptr, BB * NN, DD, DD, 1.0f);
}

// Round 7
// 385.933 us; speedup vs baseline: 1.2571x; 1.0451x over previous
//
#include <hip/hip_runtime.h>
#include <hip/hip_bf16.h>

#define BB 4
#define NN 2048
#define DD 1024
#define HH 16

using bf16 = __hip_bfloat16;
typedef __attribute__((ext_vector_type(8))) short bf16x8s;
typedef __attribute__((ext_vector_type(4))) float f32x4;

#define GLOAD_LDS16(gp, lp)                                                   \
  __builtin_amdgcn_global_load_lds(                                           \
      (const __attribute__((address_space(1))) void*)(gp),                    \
      (__attribute__((address_space(3))) void*)(lp), 16, 0, 0)

// ---------------- cast f32 -> bf16 (vectorized x4) ----------------
__global__ void cast_f32_bf16(const float* __restrict__ in, bf16* __restrict__ out, int n) {
  int i = (blockIdx.x * blockDim.x + threadIdx.x) * 4;
  if (i >= n) return;
  float4 v = *reinterpret_cast<const float4*>(in + i);
  ushort4 o;
  bf16 t0 = __float2bfloat16(v.x); o.x = *reinterpret_cast<unsigned short*>(&t0);
  bf16 t1 = __float2bfloat16(v.y); o.y = *reinterpret_cast<unsigned short*>(&t1);
  bf16 t2 = __float2bfloat16(v.z); o.z = *reinterpret_cast<unsigned short*>(&t2);
  bf16 t3 = __float2bfloat16(v.w); o.w = *reinterpret_cast<unsigned short*>(&t3);
  *reinterpret_cast<ushort4*>(out + i) = o;
}

// ---------------- transpose + cast: in[R,C] f32 -> out[C,R] bf16 ----------------
__global__ void transpose_cast(const float* __restrict__ in, bf16* __restrict__ out, int R, int C) {
  __shared__ float t[32][33];
  int c0 = blockIdx.x * 32, r0 = blockIdx.y * 32;
  int tx = threadIdx.x, ty = threadIdx.y;  // block (32,8)
#pragma unroll
  for (int i = 0; i < 4; i++)
    t[ty + i * 8][tx] = in[(size_t)(r0 + ty + i * 8) * C + c0 + tx];
  __syncthreads();
#pragma unroll
  for (int i = 0; i < 4; i++)
    out[(size_t)(c0 + ty + i * 8) * R + r0 + tx] = __float2bfloat16(t[tx][ty + i * 8]);
}

// ---------------- bf16->bf16 transpose of V into per-head layout ----------------
// Vb [B*N][D] -> Vt [B*H][64][N]  (Vt[bh][d][n] = Vb[b*N+n][h*64+d])
__global__ void transpose_v(const bf16* __restrict__ Vb, bf16* __restrict__ Vt) {
  __shared__ short t[32][33];
  int bh = blockIdx.z; int b = bh >> 4, h = bh & 15;
  int n0 = blockIdx.x * 32, d0 = blockIdx.y * 32;
  int tx = threadIdx.x, ty = threadIdx.y;  // block (32,8)
#pragma unroll
  for (int i = 0; i < 4; i++)
    t[ty + i * 8][tx] = reinterpret_cast<const short*>(Vb)[
        (size_t)(b * NN + n0 + ty + i * 8) * DD + h * 64 + d0 + tx];
  __syncthreads();
#pragma unroll
  for (int i = 0; i < 4; i++)
    reinterpret_cast<short*>(Vt)[(size_t)(bh * 64 + d0 + ty + i * 8) * NN + n0 + tx] =
        t[tx][ty + i * 8];
}

// ---------------- bf16 MFMA GEMM: C[M,Nc] = scale*(A[M,K] * BT[Nc,K]^T + bias (+rowadd)) ----
// 128x128 tile, BK=64, 4 waves (2x2). global_load_lds width=16 into linear [128][64] LDS;
// XOR chunk-swizzle on global source + ds_read. Bijective XCD swizzle (grids are %8==0).
template <int OUT_BF16, int HAS_ROWADD>
__global__ __launch_bounds__(256) void gemm_bt(
    const bf16* __restrict__ A, const bf16* __restrict__ BT, void* __restrict__ Cout,
    const float* __restrict__ bias, const float* __restrict__ rowadd,
    int M, int Nc, int K, float scale) {
  __shared__ short As[128 * 64];
  __shared__ short Bs[128 * 64];
  const int tid = threadIdx.x;
  // XCD-aware block swizzle: contiguous chunks per XCD (nwg % 8 == 0 for all launches)
  const int nbx = gridDim.x;
  const int nwg = nbx * gridDim.y;
  const int wg = blockIdx.y * nbx + blockIdx.x;
  const int swg = (wg & 7) * (nwg >> 3) + (wg >> 3);
  const int bxi = swg % nbx, byi = swg / nbx;
  const int l = tid & 63, w = tid >> 6;
  const int wr = (w >> 1) * 64, wc = (w & 1) * 64;
  const int brow = byi * 128, bcol = bxi * 128;
  const int lr = l & 15, lg = l >> 4;
  const int swz = lr & 7;
  f32x4 acc[4][4] = {};
  for (int k0 = 0; k0 < K; k0 += 64) {
#pragma unroll
    for (int i = 0; i < 4; i++) {
      int c = i * 256 + tid;          // chunk index 0..1023 (16B chunks)
      int row = c >> 3, gch = (c & 7) ^ (row & 7);
      short* lA = (short*)As + (size_t)(i * 256 + w * 64) * 8;  // wave-uniform dest
      GLOAD_LDS16(A + (size_t)(brow + row) * K + k0 + gch * 8, lA);
      short* lB = (short*)Bs + (size_t)(i * 256 + w * 64) * 8;
      GLOAD_LDS16(BT + (size_t)(bcol + row) * K + k0 + gch * 8, lB);
    }
    __syncthreads();
#pragma unroll
    for (int t = 0; t < 2; t++) {
      bf16x8s a[4], bfr[4];
#pragma unroll
      for (int m = 0; m < 4; m++)
        a[m] = *reinterpret_cast<const bf16x8s*>(
            &As[(wr + m * 16 + lr) * 64 + ((t * 4 + lg) ^ swz) * 8]);
#pragma unroll
      for (int n = 0; n < 4; n++)
        bfr[n] = *reinterpret_cast<const bf16x8s*>(
            &Bs[(wc + n * 16 + lr) * 64 + ((t * 4 + lg) ^ swz) * 8]);
#pragma unroll
      for (int m = 0; m < 4; m++)
#pragma unroll
        for (int n = 0; n < 4; n++)
          acc[m][n] = __builtin_amdgcn_mfma_f32_16x16x32_bf16(a[m], bfr[n], acc[m][n], 0, 0, 0);
    }
    __syncthreads();
  }
#pragma unroll
  for (int m = 0; m < 4; m++) {
#pragma unroll
    for (int n = 0; n < 4; n++) {
      int col = bcol + wc + n * 16 + lr;
      float bv = bias[col];
#pragma unroll
      for (int r = 0; r < 4; r++) {
        int row = brow + wr + m * 16 + (l >> 4) * 4 + r;
        float v = acc[m][n][r] + bv;
        if (HAS_ROWADD) v += rowadd[(size_t)(row & (NN - 1)) * Nc + col];
        v *= scale;
        if (OUT_BF16)
          reinterpret_cast<bf16*>(Cout)[(size_t)row * Nc + col] = __float2bfloat16(v);
        else
          reinterpret_cast<float*>(Cout)[(size_t)row * Nc + col] = v;
      }
    }
  }
}

// ---------------- flash attention, swapped-operand QK^T, async reg-staged K/V ----------------
// grid 2048 linear (XCD-swizzled -> (q-tile, h, b)). 256 thr, wave w owns 16 q-rows.
// mfma(K,Q): q = lane&15, kv on reg axis -> in-lane softmax, scalar m/l state.
// K/V prefetched to regs during compute (T14), ds_written XOR-swizzled next tile.
// log2e folded into Q scale; raw mask read directly; softmax in exp2 domain.
__global__ __launch_bounds__(256) void attn_k(
    const bf16* __restrict__ Qb, const bf16* __restrict__ Kb, const bf16* __restrict__ Vt,
    const float* __restrict__ mask, bf16* __restrict__ Ob) {
  constexpr int PPAD = 72;
  __shared__ short Ks[64 * 64];
  __shared__ short Vts[64 * 64];
  __shared__ short Ps[4][16 * PPAD];
  const int tid = threadIdx.x;
  // XCD swizzle: nwg = 2048, contiguous 256-block chunk per XCD -> K/V panels L2-fit
  const int wg = blockIdx.x;
  const int swg = (wg & 7) * 256 + (wg >> 3);
  const int q0 = (swg & 31) * 64, h = (swg >> 5) & 15, b = swg >> 9;
  const int l = tid & 63, w = tid >> 6;
  const int lr = l & 15, lg = l >> 4, lk = lg * 8;
  const int swz = lr & 7;

  // Q fragment: lane holds Q-row q = lr, k-chunk lg*8 (+32)  [B-operand of mfma(K,Q)]
  const size_t qoff = (size_t)(b * NN + q0 + w * 16 + lr) * DD + h * 64;
  bf16x8s qf0 = *reinterpret_cast<const bf16x8s*>(Qb + qoff + lk);
  bf16x8s qf1 = *reinterpret_cast<const bf16x8s*>(Qb + qoff + 32 + lk);

  f32x4 acc[4] = {};          // O^T: col q=lr, row d = s4*16 + lg*4 + r
  float mrun = -1e30f, lrun = 0.f;  // per-lane scalars (q = lr)

  const size_t kbase = (size_t)b * NN * DD + h * 64;
  const size_t vbase = (size_t)(b * HH + h) * 64 * NN;
  const float* mptr = mask + (size_t)(q0 + w * 16 + lr) * NN;  // this lane's q-row

  // staging geometry: thread covers chunks c0 = tid, c1 = 256+tid (16B chunks)
  const int r0 = tid >> 3, ch0 = tid & 7;
  const int r1 = 32 + (tid >> 3);
  // global sources (natural layout, fully coalesced)
  const bf16* kg0 = Kb + kbase + (size_t)r0 * DD + ch0 * 8;
  const bf16* kg1 = Kb + kbase + (size_t)r1 * DD + ch0 * 8;
  const bf16* vg0 = Vt + vbase + (size_t)r0 * NN + ch0 * 8;
  const bf16* vg1 = Vt + vbase + (size_t)r1 * NN + ch0 * 8;
  // LDS destinations (XOR-swizzled to match fragment reads)
  short* kw0 = &Ks[r0 * 64 + (ch0 ^ (r0 & 7)) * 8];
  short* kw1 = &Ks[r1 * 64 + (ch0 ^ (r1 & 7)) * 8];
  short* vw0 = &Vts[r0 * 64 + (ch0 ^ (r0 & 7)) * 8];
  short* vw1 = &Vts[r1 * 64 + (ch0 ^ (r1 & 7)) * 8];

  uint4 kr0, kr1, vr0, vr1;
  // prologue: prefetch tile 0
  kr0 = *reinterpret_cast<const uint4*>(kg0);
  kr1 = *reinterpret_cast<const uint4*>(kg1);
  vr0 = *reinterpret_cast<const uint4*>(vg0);
  vr1 = *reinterpret_cast<const uint4*>(vg1);

  for (int jt = 0; jt < NN; jt += 64) {
    __syncthreads();  // prior tile's readers done before overwrite
    *reinterpret_cast<uint4*>(kw0) = kr0;
    *reinterpret_cast<uint4*>(kw1) = kr1;
    *reinterpret_cast<uint4*>(vw0) = vr0;
    *reinterpret_cast<uint4*>(vw1) = vr1;
    if (jt + 64 < NN) {  // prefetch next tile; loads fly during compute below
      kr0 = *reinterpret_cast<const uint4*>(kg0 + (size_t)(jt + 64) * DD);
      kr1 = *reinterpret_cast<const uint4*>(kg1 + (size_t)(jt + 64) * DD);
      vr0 = *reinterpret_cast<const uint4*>(vg0 + jt + 64);
      vr1 = *reinterpret_cast<const uint4*>(vg1 + jt + 64);
    }
    __syncthreads();

    // S^T = K Q^T: s[jj][r] = S[kv = jt + jj*16 + lg*4 + r][q = lr]
    f32x4 s[4];
#pragma unroll
    for (int jj = 0; jj < 4; jj++) {
      bf16x8s k0 = *reinterpret_cast<const bf16x8s*>(
          &Ks[(jj * 16 + lr) * 64 + ((0 + lg) ^ swz) * 8]);
      bf16x8s k1 = *reinterpret_cast<const bf16x8s*>(
          &Ks[(jj * 16 + lr) * 64 + ((4 + lg) ^ swz) * 8]);
      f32x4 z = {0.f, 0.f, 0.f, 0.f};
      z = __builtin_amdgcn_mfma_f32_16x16x32_bf16(k0, qf0, z, 0, 0, 0);
      s[jj] = __builtin_amdgcn_mfma_f32_16x16x32_bf16(k1, qf1, z, 0, 0, 0);
    }

    // logits (log2 domain; log2e folded into Q), mask row-major float4
    float lv[4][4];
#pragma unroll
    for (int jj = 0; jj < 4; jj++) {
      float4 mv = *reinterpret_cast<const float4*>(mptr + jt + jj * 16 + lg * 4);
      lv[jj][0] = s[jj][0] * mv.x;
      lv[jj][1] = s[jj][1] * mv.y;
      lv[jj][2] = s[jj][2] * mv.z;
      lv[jj][3] = s[jj][3] * mv.w;
    }

    // full row max for q=lr: 15 in-lane fmax + 2 cross-group shuffles
    float mx0 = fmaxf(fmaxf(lv[0][0], lv[0][1]), fmaxf(lv[0][2], lv[0][3]));
    float mx1 = fmaxf(fmaxf(lv[1][0], lv[1][1]), fmaxf(lv[1][2], lv[1][3]));
    float mx2 = fmaxf(fmaxf(lv[2][0], lv[2][1]), fmaxf(lv[2][2], lv[2][3]));
    float mx3 = fmaxf(fmaxf(lv[3][0], lv[3][1]), fmaxf(lv[3][2], lv[3][3]));
    float mx = fmaxf(fmaxf(mx0, mx1), fmaxf(mx2, mx3));
    mx = fmaxf(mx, __shfl_xor(mx, 16, 64));
    mx = fmaxf(mx, __shfl_xor(mx, 32, 64));

    // defer-max: rescale only if this row grew by > 11 (log2 domain)
    if (__any(mx > mrun + 11.0f)) {
      float mnew = fmaxf(mrun, mx);
      float sc = __builtin_amdgcn_exp2f(mrun - mnew);
      mrun = mnew;
      lrun *= sc;
#pragma unroll
      for (int s4 = 0; s4 < 4; s4++)
#pragma unroll
        for (int r = 0; r < 4; r++) acc[s4][r] *= sc;
    }

    // P = exp2(lv - m): 16 values, pack 4 bf16 per jj -> one ds_write_b64 each
    short* Pw = &Ps[w][0];
    float rs = 0.f;
#pragma unroll
    for (int jj = 0; jj < 4; jj++) {
      float p0 = __builtin_amdgcn_exp2f(lv[jj][0] - mrun);
      float p1 = __builtin_amdgcn_exp2f(lv[jj][1] - mrun);
      float p2 = __builtin_amdgcn_exp2f(lv[jj][2] - mrun);
      float p3 = __builtin_amdgcn_exp2f(lv[jj][3] - mrun);
      rs += (p0 + p1) + (p2 + p3);
      ushort4 pk;
      bf16 b0 = __float2bfloat16(p0); pk.x = *reinterpret_cast<unsigned short*>(&b0);
      bf16 b1 = __float2bfloat16(p1); pk.y = *reinterpret_cast<unsigned short*>(&b1);
      bf16 b2 = __float2bfloat16(p2); pk.z = *reinterpret_cast<unsigned short*>(&b2);
      bf16 b3 = __float2bfloat16(p3); pk.w = *reinterpret_cast<unsigned short*>(&b3);
      *reinterpret_cast<ushort4*>(&Pw[lr * PPAD + jj * 16 + lg * 4]) = pk;
    }
    rs += __shfl_xor(rs, 16, 64);
    rs += __shfl_xor(rs, 32, 64);
    lrun += rs;

    // wave-private P: drain DS writes, fence the scheduler, no block barrier
    asm volatile("s_waitcnt lgkmcnt(0)" ::: "memory");
    __builtin_amdgcn_sched_barrier(0);

    // O^T += V^T P^T : A = V^T rows d, B = P rows q (lane lr)
    bf16x8s pb0 = *reinterpret_cast<const bf16x8s*>(&Pw[lr * PPAD + lk]);
    bf16x8s pb1 = *reinterpret_cast<const bf16x8s*>(&Pw[lr * PPAD + 32 + lk]);
#pragma unroll
    for (int s4 = 0; s4 < 4; s4++) {
      bf16x8s v0 = *reinterpret_cast<const bf16x8s*>(
          &Vts[(s4 * 16 + lr) * 64 + ((0 + lg) ^ swz) * 8]);
      bf16x8s v1 = *reinterpret_cast<const bf16x8s*>(
          &Vts[(s4 * 16 + lr) * 64 + ((4 + lg) ^ swz) * 8]);
      acc[s4] = __builtin_amdgcn_mfma_f32_16x16x32_bf16(v0, pb0, acc[s4], 0, 0, 0);
      acc[s4] = __builtin_amdgcn_mfma_f32_16x16x32_bf16(v1, pb1, acc[s4], 0, 0, 0);
    }
  }

  // epilogue: normalize (1 rcp/lane), pack 4 consecutive d per s4 -> 8B stores
  float rl = __builtin_amdgcn_rcpf(lrun);
  const size_t orow = (size_t)(b * NN + q0 + w * 16 + lr) * DD + h * 64;
#pragma unroll
  for (int s4 = 0; s4 < 4; s4++) {
    ushort4 o;
    bf16 b0 = __float2bfloat16(acc[s4][0] * rl); o.x = *reinterpret_cast<unsigned short*>(&b0);
    bf16 b1 = __float2bfloat16(acc[s4][1] * rl); o.y = *reinterpret_cast<unsigned short*>(&b1);
    bf16 b2 = __float2bfloat16(acc[s4][2] * rl); o.z = *reinterpret_cast<unsigned short*>(&b2);
    bf16 b3 = __float2bfloat16(acc[s4][3] * rl); o.w = *reinterpret_cast<unsigned short*>(&b3);
    *reinterpret_cast<ushort4*>(reinterpret_cast<unsigned short*>(Ob) + orow + s4 * 16 + lg * 4) = o;
  }
}

// ---------------- orchestration ----------------
extern "C" void kernel_launch(void* const* d_in, const int* in_sizes, int n_in,
                              void* d_out, int out_size, void* d_ws, size_t ws_size,
                              hipStream_t stream) {
  (void)in_sizes; (void)n_in; (void)out_size; (void)ws_size;
  const float* x    = (const float*)d_in[0];
  const float* cg   = (const float*)d_in[1];
  const float* mask = (const float*)d_in[2];
  const float* Wq   = (const float*)d_in[3];
  const float* bq   = (const float*)d_in[4];
  const float* Wk   = (const float*)d_in[5];
  const float* bk   = (const float*)d_in[6];
  const float* Wc   = (const float*)d_in[7];
  const float* bc   = (const float*)d_in[8];
  const float* We   = (const float*)d_in[9];
  const float* be   = (const float*)d_in[10];
  const float* Wv   = (const float*)d_in[11];
  const float* bv   = (const float*)d_in[12];
  const float* Wo   = (const float*)d_in[13];
  const float* bo   = (const float*)d_in[14];

  auto MB = [](size_t m) { return m << 20; };
  char* ws = (char*)d_ws;
  bf16* xb   = (bf16*)(ws + MB(0));    // 16 MB
  bf16* WqT  = (bf16*)(ws + MB(16));   // 2 MB each
  bf16* WkT  = (bf16*)(ws + MB(18));
  bf16* WvT  = (bf16*)(ws + MB(20));
  bf16* WoT  = (bf16*)(ws + MB(22));
  float* cq  = (float*)(ws + MB(24));  // 8 MB f32 (dead after Q GEMM)
  float* ck  = (float*)(ws + MB(32));  // 8 MB f32 (dead after K GEMM)
  bf16* Qb   = (bf16*)(ws + MB(40));   // 16 MB
  bf16* Kb   = (bf16*)(ws + MB(56));   // 16 MB
  bf16* Vb   = (bf16*)(ws + MB(72));   // 16 MB (dead after transpose_v)
  bf16* Vt   = (bf16*)(ws + MB(88));   // 16 MB -> peak 104 MB
  bf16* Ob   = (bf16*)(ws + MB(72));   // overlays Vb (dead)
  // overlays, dead after cq/ck GEMMs (before Qb/Kb are written):
  bf16* WcT  = (bf16*)(ws + MB(40));   // 4 MB
  bf16* WeT  = (bf16*)(ws + MB(44));   // 4 MB
  bf16* cgb  = (bf16*)(ws + MB(48));   // 8 MB
  bf16* cgT  = (bf16*)(ws + MB(56));   // 8 MB

  cast_f32_bf16<<<dim3(BB * NN * DD / 4 / 256), 256, 0, stream>>>(x, xb, BB * NN * DD);
  cast_f32_bf16<<<dim3(NN * NN / 4 / 256), 256, 0, stream>>>(cg, cgb, NN * NN);
  dim3 tb(32, 8);
  transpose_cast<<<dim3(DD / 32, DD / 32), tb, 0, stream>>>(Wq, WqT, DD, DD);
  transpose_cast<<<dim3(DD / 32, DD / 32), tb, 0, stream>>>(Wk, WkT, DD, DD);
  transpose_cast<<<dim3(DD / 32, DD / 32), tb, 0, stream>>>(Wv, WvT, DD, DD);
  transpose_cast<<<dim3(DD / 32, DD / 32), tb, 0, stream>>>(Wo, WoT, DD, DD);
  transpose_cast<<<dim3(DD / 32, NN / 32), tb, 0, stream>>>(Wc, WcT, NN, DD);
  transpose_cast<<<dim3(DD / 32, NN / 32), tb, 0, stream>>>(We, WeT, NN, DD);
  transpose_cast<<<dim3(NN / 32, NN / 32), tb, 0, stream>>>(cg, cgT, NN, NN);

  // cq = cg@Wc + bc ; ck = cg^T@We + be   (f32 out)
  gemm_bt<0, 0><<<dim3(DD / 128, NN / 128), 256, 0, stream>>>(cgb, WcT, cq, bc, nullptr, NN, DD, NN, 1.0f);
  gemm_bt<0, 0><<<dim3(DD / 128, NN / 128), 256, 0, stream>>>(cgT, WeT, ck, be, nullptr, NN, DD, NN, 1.0f);
  // Q = (0.125*log2e)*(x@Wq + bq + cq[row]) ; K = x@Wk + bk + ck[row] ; V = x@Wv + bv
  gemm_bt<1, 1><<<dim3(DD / 128, BB * NN / 128), 256, 0, stream>>>(
      xb, WqT, Qb, bq, cq, BB * NN, DD, DD, 0.125f * 1.4426950408889634f);
  gemm_bt<1, 1><<<dim3(DD / 128, BB * NN / 128), 256, 0, stream>>>(xb, WkT, Kb, bk, ck, BB * NN, DD, DD, 1.0f);
  gemm_bt<1, 0><<<dim3(DD / 128, BB * NN / 128), 256, 0, stream>>>(xb, WvT, Vb, bv, nullptr, BB * NN, DD, DD, 1.0f);

  transpose_v<<<dim3(NN / 32, 2, BB * HH), tb, 0, stream>>>(Vb, Vt);

  attn_k<<<dim3(NN / 64 * HH * BB), 256, 0, stream>>>(Qb, Kb, Vt, mask, Ob);

  // out = attn@Wo + bo  (f32 out)
  gemm_bt<0, 0><<<dim3(DD / 128, BB * NN / 128), 256, 0, stream>>>(Ob, WoT, (float*)d_out, bo, nullptr, BB * NN, DD, DD, 1.0f);
}

// Round 8
// 348.117 us; speedup vs baseline: 1.3937x; 1.1086x over previous
//
#include <hip/hip_runtime.h>
#include <hip/hip_bf16.h>

#define BB 4
#define NN 2048
#define DD 1024
#define HH 16

using bf16 = __hip_bfloat16;
typedef __attribute__((ext_vector_type(8))) short bf16x8s;
typedef __attribute__((ext_vector_type(4))) float f32x4;

#define GLOAD_LDS16(gp, lp)                                                   \
  __builtin_amdgcn_global_load_lds(                                           \
      (const __attribute__((address_space(1))) void*)(gp),                    \
      (__attribute__((address_space(3))) void*)(lp), 16, 0, 0)

// ---------------- cast f32 -> bf16 (vectorized x4) ----------------
__global__ void cast_f32_bf16(const float* __restrict__ in, bf16* __restrict__ out, int n) {
  int i = (blockIdx.x * blockDim.x + threadIdx.x) * 4;
  if (i >= n) return;
  float4 v = *reinterpret_cast<const float4*>(in + i);
  ushort4 o;
  bf16 t0 = __float2bfloat16(v.x); o.x = *reinterpret_cast<unsigned short*>(&t0);
  bf16 t1 = __float2bfloat16(v.y); o.y = *reinterpret_cast<unsigned short*>(&t1);
  bf16 t2 = __float2bfloat16(v.z); o.z = *reinterpret_cast<unsigned short*>(&t2);
  bf16 t3 = __float2bfloat16(v.w); o.w = *reinterpret_cast<unsigned short*>(&t3);
  *reinterpret_cast<ushort4*>(out + i) = o;
}

// ---------------- transpose + cast: in[R,C] f32 -> out[C,R] bf16 ----------------
__global__ void transpose_cast(const float* __restrict__ in, bf16* __restrict__ out, int R, int C) {
  __shared__ float t[32][33];
  int c0 = blockIdx.x * 32, r0 = blockIdx.y * 32;
  int tx = threadIdx.x, ty = threadIdx.y;  // block (32,8)
#pragma unroll
  for (int i = 0; i < 4; i++)
    t[ty + i * 8][tx] = in[(size_t)(r0 + ty + i * 8) * C + c0 + tx];
  __syncthreads();
#pragma unroll
  for (int i = 0; i < 4; i++)
    out[(size_t)(c0 + ty + i * 8) * R + r0 + tx] = __float2bfloat16(t[tx][ty + i * 8]);
}

// ---------------- bf16->bf16 transpose of V into per-head layout ----------------
// Vb [B*N][D] -> Vt [B*H][64][N]  (Vt[bh][d][n] = Vb[b*N+n][h*64+d])
__global__ void transpose_v(const bf16* __restrict__ Vb, bf16* __restrict__ Vt) {
  __shared__ short t[32][33];
  int bh = blockIdx.z; int b = bh >> 4, h = bh & 15;
  int n0 = blockIdx.x * 32, d0 = blockIdx.y * 32;
  int tx = threadIdx.x, ty = threadIdx.y;  // block (32,8)
#pragma unroll
  for (int i = 0; i < 4; i++)
    t[ty + i * 8][tx] = reinterpret_cast<const short*>(Vb)[
        (size_t)(b * NN + n0 + ty + i * 8) * DD + h * 64 + d0 + tx];
  __syncthreads();
#pragma unroll
  for (int i = 0; i < 4; i++)
    reinterpret_cast<short*>(Vt)[(size_t)(bh * 64 + d0 + ty + i * 8) * NN + n0 + tx] =
        t[tx][ty + i * 8];
}

// ---------------- GEMM tile body (shared by gemm_bt and gemm_dual) ----------------
template <int OUT_BF16, int HAS_ROWADD>
__device__ __forceinline__ void gemm_tile(
    const bf16* __restrict__ A, const bf16* __restrict__ BT, void* __restrict__ Cout,
    const float* __restrict__ bias, const float* __restrict__ rowadd,
    int Nc, int K, float scale, int brow, int bcol, short* As, short* Bs) {
  const int tid = threadIdx.x;
  const int l = tid & 63, w = tid >> 6;
  const int wr = (w >> 1) * 64, wc = (w & 1) * 64;
  const int lr = l & 15, lg = l >> 4;
  const int swz = lr & 7;
  f32x4 acc[4][4] = {};
  for (int k0 = 0; k0 < K; k0 += 64) {
#pragma unroll
    for (int i = 0; i < 4; i++) {
      int c = i * 256 + tid;          // chunk index 0..1023 (16B chunks)
      int row = c >> 3, gch = (c & 7) ^ (row & 7);
      short* lA = As + (size_t)(i * 256 + w * 64) * 8;  // wave-uniform dest
      GLOAD_LDS16(A + (size_t)(brow + row) * K + k0 + gch * 8, lA);
      short* lB = Bs + (size_t)(i * 256 + w * 64) * 8;
      GLOAD_LDS16(BT + (size_t)(bcol + row) * K + k0 + gch * 8, lB);
    }
    __syncthreads();
#pragma unroll
    for (int t = 0; t < 2; t++) {
      bf16x8s a[4], bfr[4];
#pragma unroll
      for (int m = 0; m < 4; m++)
        a[m] = *reinterpret_cast<const bf16x8s*>(
            &As[(wr + m * 16 + lr) * 64 + ((t * 4 + lg) ^ swz) * 8]);
#pragma unroll
      for (int n = 0; n < 4; n++)
        bfr[n] = *reinterpret_cast<const bf16x8s*>(
            &Bs[(wc + n * 16 + lr) * 64 + ((t * 4 + lg) ^ swz) * 8]);
#pragma unroll
      for (int m = 0; m < 4; m++)
#pragma unroll
        for (int n = 0; n < 4; n++)
          acc[m][n] = __builtin_amdgcn_mfma_f32_16x16x32_bf16(a[m], bfr[n], acc[m][n], 0, 0, 0);
    }
    __syncthreads();
  }
#pragma unroll
  for (int m = 0; m < 4; m++) {
#pragma unroll
    for (int n = 0; n < 4; n++) {
      int col = bcol + wc + n * 16 + lr;
      float bv = bias[col];
#pragma unroll
      for (int r = 0; r < 4; r++) {
        int row = brow + wr + m * 16 + lg * 4 + r;
        float v = acc[m][n][r] + bv;
        if (HAS_ROWADD) v += rowadd[(size_t)(row & (NN - 1)) * Nc + col];
        v *= scale;
        if (OUT_BF16)
          reinterpret_cast<bf16*>(Cout)[(size_t)row * Nc + col] = __float2bfloat16(v);
        else
          reinterpret_cast<float*>(Cout)[(size_t)row * Nc + col] = v;
      }
    }
  }
}

// ---------------- bf16 MFMA GEMM, 128x128 tile, BK=64, XCD-swizzled ----------------
template <int OUT_BF16, int HAS_ROWADD>
__global__ __launch_bounds__(256) void gemm_bt(
    const bf16* __restrict__ A, const bf16* __restrict__ BT, void* __restrict__ Cout,
    const float* __restrict__ bias, const float* __restrict__ rowadd,
    int M, int Nc, int K, float scale) {
  __shared__ short As[128 * 64];
  __shared__ short Bs[128 * 64];
  const int nbx = gridDim.x;
  const int nwg = nbx * gridDim.y;
  const int wg = blockIdx.y * nbx + blockIdx.x;
  const int swg = (wg & 7) * (nwg >> 3) + (wg >> 3);
  const int bxi = swg % nbx, byi = swg / nbx;
  gemm_tile<OUT_BF16, HAS_ROWADD>(A, BT, Cout, bias, rowadd, Nc, K, scale,
                                  byi * 128, bxi * 128, As, Bs);
}

// ---------------- dual GEMM: two independent 2048x1024x2048 GEMMs in one launch ----
// grid (8,16,2): z selects problem -> 256 blocks fill the chip (each alone = 128).
__global__ __launch_bounds__(256) void gemm_dual(
    const bf16* __restrict__ A0, const bf16* __restrict__ B0, float* __restrict__ C0,
    const float* __restrict__ bias0,
    const bf16* __restrict__ A1, const bf16* __restrict__ B1, float* __restrict__ C1,
    const float* __restrict__ bias1, int Nc, int K) {
  __shared__ short As[128 * 64];
  __shared__ short Bs[128 * 64];
  const int nbx = gridDim.x;
  const int nwg = nbx * gridDim.y;
  const int wg = blockIdx.y * nbx + blockIdx.x;
  const int swg = (wg & 7) * (nwg >> 3) + (wg >> 3);
  const int bxi = swg % nbx, byi = swg / nbx;
  if (blockIdx.z == 0)
    gemm_tile<0, 0>(A0, B0, C0, bias0, nullptr, Nc, K, 1.0f, byi * 128, bxi * 128, As, Bs);
  else
    gemm_tile<0, 0>(A1, B1, C1, bias1, nullptr, Nc, K, 1.0f, byi * 128, bxi * 128, As, Bs);
}

// ---------------- flash attention, swapped-operand QK^T, async reg-staged K/V+mask ----
// grid 2048 linear. XCD chunk with h FASTEST inside: co-resident blocks on an XCD
// share 8 K/V panels (4MB, L2-fit) AND share mask rows 8-way across h.
// mfma(K,Q): q = lane&15, kv on reg axis -> in-lane softmax, scalar m/l state.
// K/V AND mask double-buffered in registers (T14). log2e folded into Q scale.
__global__ __launch_bounds__(256) void attn_k(
    const bf16* __restrict__ Qb, const bf16* __restrict__ Kb, const bf16* __restrict__ Vt,
    const float* __restrict__ mask, bf16* __restrict__ Ob) {
  constexpr int PPAD = 72;
  __shared__ short Ks[64 * 64];
  __shared__ short Vts[64 * 64];
  __shared__ short Ps[4][16 * PPAD];
  const int tid = threadIdx.x;
  // XCD swizzle, h-fastest within chunk: x = xcd, i = intra-chunk index
  const int wg = blockIdx.x;
  const int x = wg & 7, i = wg >> 3;
  const int b = x >> 1;
  const int h = ((x & 1) << 3) | (i & 7);
  const int q0 = ((i >> 3) & 31) * 64;
  const int l = tid & 63, w = tid >> 6;
  const int lr = l & 15, lg = l >> 4, lk = lg * 8;
  const int swz = lr & 7;

  // Q fragment: lane holds Q-row q = lr, k-chunk lg*8 (+32)  [B-operand of mfma(K,Q)]
  const size_t qoff = (size_t)(b * NN + q0 + w * 16 + lr) * DD + h * 64;
  bf16x8s qf0 = *reinterpret_cast<const bf16x8s*>(Qb + qoff + lk);
  bf16x8s qf1 = *reinterpret_cast<const bf16x8s*>(Qb + qoff + 32 + lk);

  f32x4 acc[4] = {};          // O^T: col q=lr, row d = s4*16 + lg*4 + r
  float mrun = -1e30f, lrun = 0.f;  // per-lane scalars (q = lr)

  const size_t kbase = (size_t)b * NN * DD + h * 64;
  const size_t vbase = (size_t)(b * HH + h) * 64 * NN;
  const float* mptr = mask + (size_t)(q0 + w * 16 + lr) * NN + lg * 4;  // lane's q-row

  // staging geometry: thread covers chunks c0 = tid, c1 = 256+tid (16B chunks)
  const int r0 = tid >> 3, ch0 = tid & 7;
  const int r1 = 32 + (tid >> 3);
  const bf16* kg0 = Kb + kbase + (size_t)r0 * DD + ch0 * 8;
  const bf16* kg1 = Kb + kbase + (size_t)r1 * DD + ch0 * 8;
  const bf16* vg0 = Vt + vbase + (size_t)r0 * NN + ch0 * 8;
  const bf16* vg1 = Vt + vbase + (size_t)r1 * NN + ch0 * 8;
  // LDS destinations (XOR-swizzled to match fragment reads)
  short* kw0 = &Ks[r0 * 64 + (ch0 ^ (r0 & 7)) * 8];
  short* kw1 = &Ks[r1 * 64 + (ch0 ^ (r1 & 7)) * 8];
  short* vw0 = &Vts[r0 * 64 + (ch0 ^ (r0 & 7)) * 8];
  short* vw1 = &Vts[r1 * 64 + (ch0 ^ (r1 & 7)) * 8];

  uint4 kr0, kr1, vr0, vr1;
  float4 m0, m1, m2, m3;   // current tile's mask (double-buffered)
  float4 n0, n1, n2, n3;
  // prologue: prefetch tile 0
  kr0 = *reinterpret_cast<const uint4*>(kg0);
  kr1 = *reinterpret_cast<const uint4*>(kg1);
  vr0 = *reinterpret_cast<const uint4*>(vg0);
  vr1 = *reinterpret_cast<const uint4*>(vg1);
  m0 = *reinterpret_cast<const float4*>(mptr + 0);
  m1 = *reinterpret_cast<const float4*>(mptr + 16);
  m2 = *reinterpret_cast<const float4*>(mptr + 32);
  m3 = *reinterpret_cast<const float4*>(mptr + 48);

  for (int jt = 0; jt < NN; jt += 64) {
    __syncthreads();  // prior tile's readers done before overwrite
    *reinterpret_cast<uint4*>(kw0) = kr0;
    *reinterpret_cast<uint4*>(kw1) = kr1;
    *reinterpret_cast<uint4*>(vw0) = vr0;
    *reinterpret_cast<uint4*>(vw1) = vr1;
    if (jt + 64 < NN) {  // prefetch next tile; loads fly during compute below
      kr0 = *reinterpret_cast<const uint4*>(kg0 + (size_t)(jt + 64) * DD);
      kr1 = *reinterpret_cast<const uint4*>(kg1 + (size_t)(jt + 64) * DD);
      vr0 = *reinterpret_cast<const uint4*>(vg0 + jt + 64);
      vr1 = *reinterpret_cast<const uint4*>(vg1 + jt + 64);
      n0 = *reinterpret_cast<const float4*>(mptr + jt + 64 + 0);
      n1 = *reinterpret_cast<const float4*>(mptr + jt + 64 + 16);
      n2 = *reinterpret_cast<const float4*>(mptr + jt + 64 + 32);
      n3 = *reinterpret_cast<const float4*>(mptr + jt + 64 + 48);
    }
    __syncthreads();

    // S^T = K Q^T: s[jj][r] = S[kv = jt + jj*16 + lg*4 + r][q = lr]
    f32x4 s[4];
#pragma unroll
    for (int jj = 0; jj < 4; jj++) {
      bf16x8s k0 = *reinterpret_cast<const bf16x8s*>(
          &Ks[(jj * 16 + lr) * 64 + ((0 + lg) ^ swz) * 8]);
      bf16x8s k1 = *reinterpret_cast<const bf16x8s*>(
          &Ks[(jj * 16 + lr) * 64 + ((4 + lg) ^ swz) * 8]);
      f32x4 z = {0.f, 0.f, 0.f, 0.f};
      z = __builtin_amdgcn_mfma_f32_16x16x32_bf16(k0, qf0, z, 0, 0, 0);
      s[jj] = __builtin_amdgcn_mfma_f32_16x16x32_bf16(k1, qf1, z, 0, 0, 0);
    }

    // logits (log2 domain; log2e folded into Q), mask from registers
    float lv[4][4];
    lv[0][0] = s[0][0] * m0.x; lv[0][1] = s[0][1] * m0.y;
    lv[0][2] = s[0][2] * m0.z; lv[0][3] = s[0][3] * m0.w;
    lv[1][0] = s[1][0] * m1.x; lv[1][1] = s[1][1] * m1.y;
    lv[1][2] = s[1][2] * m1.z; lv[1][3] = s[1][3] * m1.w;
    lv[2][0] = s[2][0] * m2.x; lv[2][1] = s[2][1] * m2.y;
    lv[2][2] = s[2][2] * m2.z; lv[2][3] = s[2][3] * m2.w;
    lv[3][0] = s[3][0] * m3.x; lv[3][1] = s[3][1] * m3.y;
    lv[3][2] = s[3][2] * m3.z; lv[3][3] = s[3][3] * m3.w;
    m0 = n0; m1 = n1; m2 = n2; m3 = n3;

    // full row max for q=lr: 15 in-lane fmax + 2 cross-group shuffles
    float mx0 = fmaxf(fmaxf(lv[0][0], lv[0][1]), fmaxf(lv[0][2], lv[0][3]));
    float mx1 = fmaxf(fmaxf(lv[1][0], lv[1][1]), fmaxf(lv[1][2], lv[1][3]));
    float mx2 = fmaxf(fmaxf(lv[2][0], lv[2][1]), fmaxf(lv[2][2], lv[2][3]));
    float mx3 = fmaxf(fmaxf(lv[3][0], lv[3][1]), fmaxf(lv[3][2], lv[3][3]));
    float mx = fmaxf(fmaxf(mx0, mx1), fmaxf(mx2, mx3));
    mx = fmaxf(mx, __shfl_xor(mx, 16, 64));
    mx = fmaxf(mx, __shfl_xor(mx, 32, 64));

    // defer-max: rescale only if this row grew by > 11 (log2 domain)
    if (__any(mx > mrun + 11.0f)) {
      float mnew = fmaxf(mrun, mx);
      float sc = __builtin_amdgcn_exp2f(mrun - mnew);
      mrun = mnew;
      lrun *= sc;
#pragma unroll
      for (int s4 = 0; s4 < 4; s4++)
#pragma unroll
        for (int r = 0; r < 4; r++) acc[s4][r] *= sc;
    }

    // P = exp2(lv - m): 16 values, pack 4 bf16 per jj -> one ds_write_b64 each
    short* Pw = &Ps[w][0];
    float rs = 0.f;
#pragma unroll
    for (int jj = 0; jj < 4; jj++) {
      float p0 = __builtin_amdgcn_exp2f(lv[jj][0] - mrun);
      float p1 = __builtin_amdgcn_exp2f(lv[jj][1] - mrun);
      float p2 = __builtin_amdgcn_exp2f(lv[jj][2] - mrun);
      float p3 = __builtin_amdgcn_exp2f(lv[jj][3] - mrun);
      rs += (p0 + p1) + (p2 + p3);
      ushort4 pk;
      bf16 b0 = __float2bfloat16(p0); pk.x = *reinterpret_cast<unsigned short*>(&b0);
      bf16 b1 = __float2bfloat16(p1); pk.y = *reinterpret_cast<unsigned short*>(&b1);
      bf16 b2 = __float2bfloat16(p2); pk.z = *reinterpret_cast<unsigned short*>(&b2);
      bf16 b3 = __float2bfloat16(p3); pk.w = *reinterpret_cast<unsigned short*>(&b3);
      *reinterpret_cast<ushort4*>(&Pw[lr * PPAD + jj * 16 + lg * 4]) = pk;
    }
    rs += __shfl_xor(rs, 16, 64);
    rs += __shfl_xor(rs, 32, 64);
    lrun += rs;

    // wave-private P: drain DS writes, fence the scheduler, no block barrier
    asm volatile("s_waitcnt lgkmcnt(0)" ::: "memory");
    __builtin_amdgcn_sched_barrier(0);

    // O^T += V^T P^T : A = V^T rows d, B = P rows q (lane lr)
    bf16x8s pb0 = *reinterpret_cast<const bf16x8s*>(&Pw[lr * PPAD + lk]);
    bf16x8s pb1 = *reinterpret_cast<const bf16x8s*>(&Pw[lr * PPAD + 32 + lk]);
#pragma unroll
    for (int s4 = 0; s4 < 4; s4++) {
      bf16x8s v0 = *reinterpret_cast<const bf16x8s*>(
          &Vts[(s4 * 16 + lr) * 64 + ((0 + lg) ^ swz) * 8]);
      bf16x8s v1 = *reinterpret_cast<const bf16x8s*>(
          &Vts[(s4 * 16 + lr) * 64 + ((4 + lg) ^ swz) * 8]);
      acc[s4] = __builtin_amdgcn_mfma_f32_16x16x32_bf16(v0, pb0, acc[s4], 0, 0, 0);
      acc[s4] = __builtin_amdgcn_mfma_f32_16x16x32_bf16(v1, pb1, acc[s4], 0, 0, 0);
    }
  }

  // epilogue: normalize (1 rcp/lane), pack 4 consecutive d per s4 -> 8B stores
  float rl = __builtin_amdgcn_rcpf(lrun);
  const size_t orow = (size_t)(b * NN + q0 + w * 16 + lr) * DD + h * 64;
#pragma unroll
  for (int s4 = 0; s4 < 4; s4++) {
    ushort4 o;
    bf16 b0 = __float2bfloat16(acc[s4][0] * rl); o.x = *reinterpret_cast<unsigned short*>(&b0);
    bf16 b1 = __float2bfloat16(acc[s4][1] * rl); o.y = *reinterpret_cast<unsigned short*>(&b1);
    bf16 b2 = __float2bfloat16(acc[s4][2] * rl); o.z = *reinterpret_cast<unsigned short*>(&b2);
    bf16 b3 = __float2bfloat16(acc[s4][3] * rl); o.w = *reinterpret_cast<unsigned short*>(&b3);
    *reinterpret_cast<ushort4*>(reinterpret_cast<unsigned short*>(Ob) + orow + s4 * 16 + lg * 4) = o;
  }
}

// ---------------- orchestration ----------------
extern "C" void kernel_launch(void* const* d_in, const int* in_sizes, int n_in,
                              void* d_out, int out_size, void* d_ws, size_t ws_size,
                              hipStream_t stream) {
  (void)in_sizes; (void)n_in; (void)out_size; (void)ws_size;
  const float* x    = (const float*)d_in[0];
  const float* cg   = (const float*)d_in[1];
  const float* mask = (const float*)d_in[2];
  const float* Wq   = (const float*)d_in[3];
  const float* bq   = (const float*)d_in[4];
  const float* Wk   = (const float*)d_in[5];
  const float* bk   = (const float*)d_in[6];
  const float* Wc   = (const float*)d_in[7];
  const float* bc   = (const float*)d_in[8];
  const float* We   = (const float*)d_in[9];
  const float* be   = (const float*)d_in[10];
  const float* Wv   = (const float*)d_in[11];
  const float* bv   = (const float*)d_in[12];
  const float* Wo   = (const float*)d_in[13];
  const float* bo   = (const float*)d_in[14];

  auto MB = [](size_t m) { return m << 20; };
  char* ws = (char*)d_ws;
  bf16* xb   = (bf16*)(ws + MB(0));    // 16 MB
  bf16* WqT  = (bf16*)(ws + MB(16));   // 2 MB each
  bf16* WkT  = (bf16*)(ws + MB(18));
  bf16* WvT  = (bf16*)(ws + MB(20));
  bf16* WoT  = (bf16*)(ws + MB(22));
  float* cq  = (float*)(ws + MB(24));  // 8 MB f32 (dead after Q GEMM)
  float* ck  = (float*)(ws + MB(32));  // 8 MB f32 (dead after K GEMM)
  bf16* Qb   = (bf16*)(ws + MB(40));   // 16 MB
  bf16* Kb   = (bf16*)(ws + MB(56));   // 16 MB
  bf16* Vb   = (bf16*)(ws + MB(72));   // 16 MB (dead after transpose_v)
  bf16* Vt   = (bf16*)(ws + MB(88));   // 16 MB -> peak 104 MB
  bf16* Ob   = (bf16*)(ws + MB(72));   // overlays Vb (dead)
  // overlays, dead after cq/ck GEMMs (before Qb/Kb are written):
  bf16* WcT  = (bf16*)(ws + MB(40));   // 4 MB
  bf16* WeT  = (bf16*)(ws + MB(44));   // 4 MB
  bf16* cgb  = (bf16*)(ws + MB(48));   // 8 MB
  bf16* cgT  = (bf16*)(ws + MB(56));   // 8 MB

  cast_f32_bf16<<<dim3(BB * NN * DD / 4 / 256), 256, 0, stream>>>(x, xb, BB * NN * DD);
  cast_f32_bf16<<<dim3(NN * NN / 4 / 256), 256, 0, stream>>>(cg, cgb, NN * NN);
  dim3 tb(32, 8);
  transpose_cast<<<dim3(DD / 32, DD / 32), tb, 0, stream>>>(Wq, WqT, DD, DD);
  transpose_cast<<<dim3(DD / 32, DD / 32), tb, 0, stream>>>(Wk, WkT, DD, DD);
  transpose_cast<<<dim3(DD / 32, DD / 32), tb, 0, stream>>>(Wv, WvT, DD, DD);
  transpose_cast<<<dim3(DD / 32, DD / 32), tb, 0, stream>>>(Wo, WoT, DD, DD);
  transpose_cast<<<dim3(DD / 32, NN / 32), tb, 0, stream>>>(Wc, WcT, NN, DD);
  transpose_cast<<<dim3(DD / 32, NN / 32), tb, 0, stream>>>(We, WeT, NN, DD);
  transpose_cast<<<dim3(NN / 32, NN / 32), tb, 0, stream>>>(cg, cgT, NN, NN);

  // cq = cg@Wc + bc AND ck = cg^T@We + be in one full-chip launch (256 blocks)
  gemm_dual<<<dim3(DD / 128, NN / 128, 2), 256, 0, stream>>>(
      cgb, WcT, cq, bc, cgT, WeT, ck, be, DD, NN);
  // Q = (0.125*log2e)*(x@Wq + bq + cq[row]) ; K = x@Wk + bk + ck[row] ; V = x@Wv + bv
  gemm_bt<1, 1><<<dim3(DD / 128, BB * NN / 128), 256, 0, stream>>>(
      xb, WqT, Qb, bq, cq, BB * NN, DD, DD, 0.125f * 1.4426950408889634f);
  gemm_bt<1, 1><<<dim3(DD / 128, BB * NN / 128), 256, 0, stream>>>(xb, WkT, Kb, bk, ck, BB * NN, DD, DD, 1.0f);
  gemm_bt<1, 0><<<dim3(DD / 128, BB * NN / 128), 256, 0, stream>>>(xb, WvT, Vb, bv, nullptr, BB * NN, DD, DD, 1.0f);

  transpose_v<<<dim3(NN / 32, 2, BB * HH), tb, 0, stream>>>(Vb, Vt);

  attn_k<<<dim3(NN / 64 * HH * BB), 256, 0, stream>>>(Qb, Kb, Vt, mask, Ob);

  // out = attn@Wo + bo  (f32 out)
  gemm_bt<0, 0><<<dim3(DD / 128, BB * NN / 128), 256, 0, stream>>>(Ob, WoT, (float*)d_out, bo, nullptr, BB * NN, DD, DD, 1.0f);
}